// Round 1
// baseline (4210.892 us; speedup 1.0000x reference)
//
#include <hip/hip_runtime.h>
#include <hip/hip_bf16.h>
#include <math.h>

#define SEQ_LEN 1024
#define BATCH_N 8
#define DMODEL 256
#define DINNER 512
#define DSTATE 16
#define DTRANK 16
#define ROWS (BATCH_N * SEQ_LEN)   // 8192

__device__ __forceinline__ float siluf(float x) { return x / (1.f + expf(-x)); }
__device__ __forceinline__ float softplusf(float x) {
    return fmaxf(x, 0.f) + log1pf(expf(-fabsf(x)));
}

// C[M,N] = act(A[M,K] @ B[N,K]^T + bias)
// 128x128 tile, 256 threads, 8x8 per thread (2x2 blocks of 4x4 at stride 64).
// M % 128 == 0, K % 16 == 0 assumed; N guarded.
template<int ACT>   // 0 = none, 1 = softplus
__global__ __launch_bounds__(256) void gemm_bt(
    const float* __restrict__ A, const float* __restrict__ B,
    const float* __restrict__ bias, float* __restrict__ C,
    int M, int N, int K, int lda, int ldb, int ldc)
{
    __shared__ float As[16][128];
    __shared__ float Bs[16][128];
    const int tid = threadIdx.x;
    const int bm = blockIdx.y * 128;
    const int bn = blockIdx.x * 128;
    const int tm = tid >> 4;      // 0..15
    const int tn = tid & 15;      // 0..15

    float acc[8][8];
#pragma unroll
    for (int i = 0; i < 8; i++)
#pragma unroll
        for (int j = 0; j < 8; j++) acc[i][j] = 0.f;

    for (int k0 = 0; k0 < K; k0 += 16) {
#pragma unroll
        for (int it = 0; it < 2; ++it) {
            int s = tid + it * 256;          // 0..511 float4-slots
            int row = s >> 2;                // 0..127
            int c4  = (s & 3) << 2;          // 0,4,8,12
            float4 va = *(const float4*)(A + (size_t)(bm + row) * lda + k0 + c4);
            As[c4 + 0][row] = va.x; As[c4 + 1][row] = va.y;
            As[c4 + 2][row] = va.z; As[c4 + 3][row] = va.w;
            float4 vb;
            if (bn + row < N)
                vb = *(const float4*)(B + (size_t)(bn + row) * ldb + k0 + c4);
            else
                vb = make_float4(0.f, 0.f, 0.f, 0.f);
            Bs[c4 + 0][row] = vb.x; Bs[c4 + 1][row] = vb.y;
            Bs[c4 + 2][row] = vb.z; Bs[c4 + 3][row] = vb.w;
        }
        __syncthreads();
#pragma unroll
        for (int k = 0; k < 16; k++) {
            float a[8], bb[8];
            *(float4*)&a[0]  = *(const float4*)&As[k][tm * 4];
            *(float4*)&a[4]  = *(const float4*)&As[k][tm * 4 + 64];
            *(float4*)&bb[0] = *(const float4*)&Bs[k][tn * 4];
            *(float4*)&bb[4] = *(const float4*)&Bs[k][tn * 4 + 64];
#pragma unroll
            for (int i = 0; i < 8; i++)
#pragma unroll
                for (int j = 0; j < 8; j++)
                    acc[i][j] = fmaf(a[i], bb[j], acc[i][j]);
        }
        __syncthreads();
    }

#pragma unroll
    for (int i = 0; i < 8; i++) {
        int r = bm + tm * 4 + ((i < 4) ? i : (60 + i));  // i>=4 -> +64
        float* crow = C + (size_t)r * ldc;
#pragma unroll
        for (int jj = 0; jj < 2; jj++) {
            int c = bn + tn * 4 + jj * 64;
            float v0 = acc[i][jj * 4 + 0], v1 = acc[i][jj * 4 + 1];
            float v2 = acc[i][jj * 4 + 2], v3 = acc[i][jj * 4 + 3];
            if (c + 3 < N) {
                if (bias) { v0 += bias[c]; v1 += bias[c + 1]; v2 += bias[c + 2]; v3 += bias[c + 3]; }
                if (ACT == 1) { v0 = softplusf(v0); v1 = softplusf(v1); v2 = softplusf(v2); v3 = softplusf(v3); }
                *(float4*)(crow + c) = make_float4(v0, v1, v2, v3);
            } else {
                float vv[4] = {v0, v1, v2, v3};
                for (int j = 0; j < 4; j++) {
                    if (c + j < N) {
                        float v = vv[j];
                        if (bias) v += bias[c + j];
                        if (ACT == 1) v = softplusf(v);
                        crow[c + j] = v;
                    }
                }
            }
        }
    }
}

// causal depthwise conv (k=4) + bias + silu.  xz: [ROWS][1024], xh = cols 0..511
__global__ __launch_bounds__(256) void conv_silu_k(
    const float* __restrict__ xz, const float* __restrict__ cw,
    const float* __restrict__ cb, float* __restrict__ xc)
{
    int idx = blockIdx.x * 256 + threadIdx.x;   // < ROWS*DINNER
    int d = idx & (DINNER - 1);
    int row = idx >> 9;
    int t = row & (SEQ_LEN - 1);
    float4 w = *(const float4*)(cw + d * 4);
    float acc = cb[d];
    const float* p = xz + (size_t)row * 1024 + d;
    if (t >= 3) acc = fmaf(p[-3 * 1024], w.x, acc);
    if (t >= 2) acc = fmaf(p[-2 * 1024], w.y, acc);
    if (t >= 1) acc = fmaf(p[-1 * 1024], w.z, acc);
    acc = fmaf(p[0], w.w, acc);
    xc[idx] = siluf(acc);
}

// selective scan: 16 lanes per (b,d) channel (one per state n).
// grid = 8 batches * 32 dgroups; block = 256 threads = 16 channels.
// writes y*silu(z) into xz cols 0..511 (xh half is dead after conv).
__global__ __launch_bounds__(256) void scan_k(
    const float* __restrict__ dt,    // [ROWS][512]
    const float* __restrict__ xc,    // [ROWS][512]
    const float* __restrict__ xdbl,  // [ROWS][48]  (B at +16, C at +32)
    float* __restrict__ xz,          // [ROWS][1024]  z at +512, y out at col d
    const float* __restrict__ A_log, // [512][16]
    const float* __restrict__ Dp)    // [512]
{
    const int tid  = threadIdx.x;
    const int n    = tid & 15;
    const int dloc = tid >> 4;                 // 0..15
    const int b    = blockIdx.x >> 5;          // 0..7
    const int dg   = blockIdx.x & 31;          // 0..31
    const int d    = dg * 16 + dloc;
    const float An = -expf(A_log[d * 16 + n]);
    const float Dd = Dp[d];
    float h = 0.f;
    const int base = b * SEQ_LEN;
    for (int t = 0; t < SEQ_LEN; ++t) {
        const int row = base + t;
        float dtv = dt[(size_t)row * 512 + d];
        float xcv = xc[(size_t)row * 512 + d];
        float Bn  = xdbl[(size_t)row * 48 + 16 + n];
        float Cn  = xdbl[(size_t)row * 48 + 32 + n];
        float dA  = expf(dtv * An);
        h = fmaf(dA, h, dtv * xcv * Bn);
        float yp = h * Cn;
        yp += __shfl_xor(yp, 1, 16);
        yp += __shfl_xor(yp, 2, 16);
        yp += __shfl_xor(yp, 4, 16);
        yp += __shfl_xor(yp, 8, 16);
        if (n == 0) {
            float yv = fmaf(Dd, xcv, yp);
            float zv = xz[(size_t)row * 1024 + 512 + d];
            yv *= siluf(zv);
            xz[(size_t)row * 1024 + d] = yv;
        }
    }
}

// LayerNorm over 256 features; one wave per row, 4 rows per block.
__global__ __launch_bounds__(256) void ln_k(
    const float* __restrict__ X, const float* __restrict__ g,
    const float* __restrict__ b2, float* __restrict__ Y)
{
    int lane = threadIdx.x & 63;
    int row = blockIdx.x * 4 + (threadIdx.x >> 6);
    const float4 v = *(const float4*)(X + (size_t)row * 256 + lane * 4);
    float s = v.x + v.y + v.z + v.w;
    float q = v.x * v.x + v.y * v.y + v.z * v.z + v.w * v.w;
#pragma unroll
    for (int o = 1; o < 64; o <<= 1) { s += __shfl_xor(s, o, 64); q += __shfl_xor(q, o, 64); }
    float mean = s * (1.f / 256.f);
    float var = q * (1.f / 256.f) - mean * mean;
    float inv = rsqrtf(var + 1e-5f);
    float4 gg = *(const float4*)(g + lane * 4);
    float4 bb = *(const float4*)(b2 + lane * 4);
    float4 o4;
    o4.x = (v.x - mean) * inv * gg.x + bb.x;
    o4.y = (v.y - mean) * inv * gg.y + bb.y;
    o4.z = (v.z - mean) * inv * gg.z + bb.z;
    o4.w = (v.w - mean) * inv * gg.w + bb.w;
    *(float4*)(Y + (size_t)row * 256 + lane * 4) = o4;
}

// mean over seq then dot with Wf + bf. one block per batch.
__global__ __launch_bounds__(256) void final_k(
    const float* __restrict__ H, const float* __restrict__ Wf,
    const float* __restrict__ bf, float* __restrict__ out)
{
    int b = blockIdx.x;
    int c = threadIdx.x;
    const float* p = H + (size_t)b * SEQ_LEN * 256 + c;
    float s = 0.f;
    for (int t = 0; t < SEQ_LEN; t++) s += p[t * 256];
    float v = s * (1.f / 1024.f) * Wf[c];
    int lane = c & 63;
#pragma unroll
    for (int o = 1; o < 64; o <<= 1) v += __shfl_xor(v, o, 64);
    __shared__ float red[4];
    if (lane == 0) red[c >> 6] = v;
    __syncthreads();
    if (c == 0) out[b] = red[0] + red[1] + red[2] + red[3] + bf[0];
}

extern "C" void kernel_launch(void* const* d_in, const int* in_sizes, int n_in,
                              void* d_out, int out_size, void* d_ws, size_t ws_size,
                              hipStream_t stream)
{
    const float* x      = (const float*)d_in[0];
    const float* Wp     = (const float*)d_in[1];
    const float* bp     = (const float*)d_in[2];
    const float* W_in   = (const float*)d_in[3];
    const float* conv_w = (const float*)d_in[4];
    const float* conv_b = (const float*)d_in[5];
    const float* W_x    = (const float*)d_in[6];
    const float* W_dt   = (const float*)d_in[7];
    const float* b_dt   = (const float*)d_in[8];
    const float* A_log  = (const float*)d_in[9];
    const float* Dp     = (const float*)d_in[10];
    const float* W_out  = (const float*)d_in[11];
    const float* ln_g   = (const float*)d_in[12];
    const float* ln_b   = (const float*)d_in[13];
    const float* Wf     = (const float*)d_in[14];
    const float* bf     = (const float*)d_in[15];

    float* ws = (float*)d_ws;
    float* bufXZ = ws;                             // 8192*1024 = 8388608
    float* bufXC = bufXZ + (size_t)ROWS * 1024;    // 8192*512
    float* bufDT = bufXC + (size_t)ROWS * 512;     // 8192*512
    float* bufXD = bufDT + (size_t)ROWS * 512;     // 8192*48
    float* bufH  = bufXD + (size_t)ROWS * 48;      // 8192*256
    // post-GEMM output (pre-LN) reuses bufXC's space?  No: bufXC still live
    // until scan is done; W_out GEMM runs after scan, so reuse bufXC.
    float* bufO  = bufXC;                          // [ROWS][256] overlays dead xc

    dim3 blk(256);

    // h = x @ Wp^T + bp    (M=8192,N=256,K=64)
    gemm_bt<0><<<dim3(2, 64), blk, 0, stream>>>(x, Wp, bp, bufH,
                                                ROWS, DMODEL, 64, 64, 64, DMODEL);

    for (int l = 0; l < 4; ++l) {
        const float* Wi  = W_in   + (size_t)l * 2 * DINNER * DMODEL;
        const float* cw  = conv_w + (size_t)l * DINNER * 4;
        const float* cb  = conv_b + (size_t)l * DINNER;
        const float* Wx  = W_x    + (size_t)l * (DTRANK + 2 * DSTATE) * DINNER;
        const float* Wdt = W_dt   + (size_t)l * DINNER * DTRANK;
        const float* bdt = b_dt   + (size_t)l * DINNER;
        const float* Al  = A_log  + (size_t)l * DINNER * DSTATE;
        const float* Dl  = Dp     + (size_t)l * DINNER;
        const float* Wo  = W_out  + (size_t)l * DMODEL * DINNER;
        const float* lg  = ln_g   + (size_t)l * DMODEL;
        const float* lb  = ln_b   + (size_t)l * DMODEL;

        // xz = h @ W_in^T   (N=1024, K=256)
        gemm_bt<0><<<dim3(8, 64), blk, 0, stream>>>(bufH, Wi, nullptr, bufXZ,
                                                    ROWS, 1024, DMODEL, DMODEL, DMODEL, 1024);
        // conv + silu -> xc
        conv_silu_k<<<dim3(ROWS * DINNER / 256), blk, 0, stream>>>(bufXZ, cw, cb, bufXC);
        // x_dbl = xc @ W_x^T  (N=48, K=512)
        gemm_bt<0><<<dim3(1, 64), blk, 0, stream>>>(bufXC, Wx, nullptr, bufXD,
                                                    ROWS, 48, DINNER, DINNER, DINNER, 48);
        // dt = softplus(dtr @ W_dt^T + b_dt)  (N=512, K=16, lda=48)
        gemm_bt<1><<<dim3(4, 64), blk, 0, stream>>>(bufXD, Wdt, bdt, bufDT,
                                                    ROWS, DINNER, DTRANK, 48, DTRANK, DINNER);
        // selective scan -> y*silu(z) into bufXZ cols 0..511
        scan_k<<<dim3(256), blk, 0, stream>>>(bufDT, bufXC, bufXD, bufXZ, Al, Dl);
        // out = y @ W_out^T  (N=256, K=512, lda=1024) -> bufO (overlays xc)
        gemm_bt<0><<<dim3(2, 64), blk, 0, stream>>>(bufXZ, Wo, nullptr, bufO,
                                                    ROWS, DMODEL, DINNER, 1024, DINNER, DMODEL);
        // layernorm -> bufH
        ln_k<<<dim3(ROWS / 4), blk, 0, stream>>>(bufO, lg, lb, bufH);
    }

    final_k<<<dim3(BATCH_N), blk, 0, stream>>>(bufH, Wf, bf, (float*)d_out);

    (void)in_sizes; (void)n_in; (void)out_size; (void)ws_size;
}

// Round 2
// 2014.889 us; speedup vs baseline: 2.0899x; 2.0899x over previous
//
#include <hip/hip_runtime.h>
#include <hip/hip_bf16.h>
#include <math.h>

#define SEQ_LEN 1024
#define BATCH_N 8
#define DMODEL 256
#define DINNER 512
#define DSTATE 16
#define DTRANK 16
#define ROWS (BATCH_N * SEQ_LEN)   // 8192
#define NCHUNK 16
#define CHUNK (SEQ_LEN / NCHUNK)   // 64

__device__ __forceinline__ float siluf(float x) { return x / (1.f + expf(-x)); }
__device__ __forceinline__ float softplusf(float x) {
    return fmaxf(x, 0.f) + log1pf(expf(-fabsf(x)));
}

// C[M,N] = act(A[M,K] @ B[N,K]^T + bias)
// 128x128 tile, 256 threads, 8x8 per thread (2x2 blocks of 4x4 at stride 64).
// M % 128 == 0, K % 16 == 0 assumed; N guarded.
template<int ACT>   // 0 = none, 1 = softplus
__global__ __launch_bounds__(256) void gemm_bt(
    const float* __restrict__ A, const float* __restrict__ B,
    const float* __restrict__ bias, float* __restrict__ C,
    int M, int N, int K, int lda, int ldb, int ldc)
{
    __shared__ float As[16][128];
    __shared__ float Bs[16][128];
    const int tid = threadIdx.x;
    const int bm = blockIdx.y * 128;
    const int bn = blockIdx.x * 128;
    const int tm = tid >> 4;      // 0..15
    const int tn = tid & 15;      // 0..15

    float acc[8][8];
#pragma unroll
    for (int i = 0; i < 8; i++)
#pragma unroll
        for (int j = 0; j < 8; j++) acc[i][j] = 0.f;

    for (int k0 = 0; k0 < K; k0 += 16) {
#pragma unroll
        for (int it = 0; it < 2; ++it) {
            int s = tid + it * 256;          // 0..511 float4-slots
            int row = s >> 2;                // 0..127
            int c4  = (s & 3) << 2;          // 0,4,8,12
            float4 va = *(const float4*)(A + (size_t)(bm + row) * lda + k0 + c4);
            As[c4 + 0][row] = va.x; As[c4 + 1][row] = va.y;
            As[c4 + 2][row] = va.z; As[c4 + 3][row] = va.w;
            float4 vb;
            if (bn + row < N)
                vb = *(const float4*)(B + (size_t)(bn + row) * ldb + k0 + c4);
            else
                vb = make_float4(0.f, 0.f, 0.f, 0.f);
            Bs[c4 + 0][row] = vb.x; Bs[c4 + 1][row] = vb.y;
            Bs[c4 + 2][row] = vb.z; Bs[c4 + 3][row] = vb.w;
        }
        __syncthreads();
#pragma unroll
        for (int k = 0; k < 16; k++) {
            float a[8], bb[8];
            *(float4*)&a[0]  = *(const float4*)&As[k][tm * 4];
            *(float4*)&a[4]  = *(const float4*)&As[k][tm * 4 + 64];
            *(float4*)&bb[0] = *(const float4*)&Bs[k][tn * 4];
            *(float4*)&bb[4] = *(const float4*)&Bs[k][tn * 4 + 64];
#pragma unroll
            for (int i = 0; i < 8; i++)
#pragma unroll
                for (int j = 0; j < 8; j++)
                    acc[i][j] = fmaf(a[i], bb[j], acc[i][j]);
        }
        __syncthreads();
    }

#pragma unroll
    for (int i = 0; i < 8; i++) {
        int r = bm + tm * 4 + ((i < 4) ? i : (60 + i));  // i>=4 -> +64
        float* crow = C + (size_t)r * ldc;
#pragma unroll
        for (int jj = 0; jj < 2; jj++) {
            int c = bn + tn * 4 + jj * 64;
            float v0 = acc[i][jj * 4 + 0], v1 = acc[i][jj * 4 + 1];
            float v2 = acc[i][jj * 4 + 2], v3 = acc[i][jj * 4 + 3];
            if (c + 3 < N) {
                if (bias) { v0 += bias[c]; v1 += bias[c + 1]; v2 += bias[c + 2]; v3 += bias[c + 3]; }
                if (ACT == 1) { v0 = softplusf(v0); v1 = softplusf(v1); v2 = softplusf(v2); v3 = softplusf(v3); }
                *(float4*)(crow + c) = make_float4(v0, v1, v2, v3);
            } else {
                float vv[4] = {v0, v1, v2, v3};
                for (int j = 0; j < 4; j++) {
                    if (c + j < N) {
                        float v = vv[j];
                        if (bias) v += bias[c + j];
                        if (ACT == 1) v = softplusf(v);
                        crow[c + j] = v;
                    }
                }
            }
        }
    }
}

// causal depthwise conv (k=4) + bias + silu.  xz: [ROWS][1024], xh = cols 0..511
__global__ __launch_bounds__(256) void conv_silu_k(
    const float* __restrict__ xz, const float* __restrict__ cw,
    const float* __restrict__ cb, float* __restrict__ xc)
{
    int idx = blockIdx.x * 256 + threadIdx.x;   // < ROWS*DINNER
    int d = idx & (DINNER - 1);
    int row = idx >> 9;
    int t = row & (SEQ_LEN - 1);
    float4 w = *(const float4*)(cw + d * 4);
    float acc = cb[d];
    const float* p = xz + (size_t)row * 1024 + d;
    if (t >= 3) acc = fmaf(p[-3 * 1024], w.x, acc);
    if (t >= 2) acc = fmaf(p[-2 * 1024], w.y, acc);
    if (t >= 1) acc = fmaf(p[-1 * 1024], w.z, acc);
    acc = fmaf(p[0], w.w, acc);
    xc[idx] = siluf(acc);
}

// Chunked selective scan: one block per (b,d); 256 threads = 16 chunks x 16 n.
// Phase A: per-thread local scan of 64 steps -> (P = prod dA, S = local state).
// Phase B: 16-step LDS scan over chunks -> incoming state h0 per chunk.
// Phase C: re-scan chunk from h0, emit y = (sum_n h*C) + D*xc, y *= silu(z).
__global__ __launch_bounds__(256) void scan_k(
    const float* __restrict__ dt,    // [ROWS][512]
    const float* __restrict__ xc,    // [ROWS][512]
    const float* __restrict__ xdbl,  // [ROWS][48]  (B at +16, C at +32)
    float* __restrict__ xz,          // [ROWS][1024]  z at +512, y out at col d
    const float* __restrict__ A_log, // [512][16]
    const float* __restrict__ Dp)    // [512]
{
    const int tid   = threadIdx.x;
    const int n     = tid & 15;
    const int chunk = tid >> 4;                // 0..15
    const int b     = blockIdx.x >> 9;         // 0..7
    const int d     = blockIdx.x & 511;        // 0..511

    const float An = -expf(A_log[d * 16 + n]);
    const int t0 = b * SEQ_LEN + chunk * CHUNK;   // first row of my chunk

    __shared__ float ldsP[NCHUNK][DSTATE];
    __shared__ float ldsS[NCHUNK][DSTATE];
    __shared__ float ldsH0[NCHUNK][DSTATE];

    // ---- Phase A: local chunk scan with h0 = 0 ----
    float suma = 0.f, S = 0.f;
#pragma unroll 4
    for (int t = 0; t < CHUNK; ++t) {
        const size_t row = (size_t)(t0 + t);
        float dtv = dt[row * 512 + d];
        float xcv = xc[row * 512 + d];
        float Bn  = xdbl[row * 48 + 16 + n];
        float a   = dtv * An;
        suma += a;
        S = fmaf(expf(a), S, dtv * xcv * Bn);
    }
    ldsP[chunk][n] = expf(suma);
    ldsS[chunk][n] = S;
    __syncthreads();

    // ---- Phase B: sequential combine over 16 chunks (16 lanes active) ----
    if (tid < 16) {
        float h = 0.f;
#pragma unroll
        for (int c = 0; c < NCHUNK; ++c) {
            ldsH0[c][tid] = h;
            h = fmaf(ldsP[c][tid], h, ldsS[c][tid]);
        }
    }
    __syncthreads();

    // ---- Phase C: re-scan with correct incoming state, emit y ----
    const float Dd = Dp[d];
    float h = ldsH0[chunk][n];
#pragma unroll 2
    for (int t = 0; t < CHUNK; ++t) {
        const size_t row = (size_t)(t0 + t);
        float dtv = dt[row * 512 + d];
        float xcv = xc[row * 512 + d];
        float Bn  = xdbl[row * 48 + 16 + n];
        float Cn  = xdbl[row * 48 + 32 + n];
        float dA  = expf(dtv * An);
        h = fmaf(dA, h, dtv * xcv * Bn);
        float yp = h * Cn;
        yp += __shfl_xor(yp, 1, 16);
        yp += __shfl_xor(yp, 2, 16);
        yp += __shfl_xor(yp, 4, 16);
        yp += __shfl_xor(yp, 8, 16);
        if (n == 0) {
            float yv = fmaf(Dd, xcv, yp);
            float zv = xz[row * 1024 + 512 + d];
            yv *= siluf(zv);
            xz[row * 1024 + d] = yv;
        }
    }
}

// LayerNorm over 256 features; one wave per row, 4 rows per block.
__global__ __launch_bounds__(256) void ln_k(
    const float* __restrict__ X, const float* __restrict__ g,
    const float* __restrict__ b2, float* __restrict__ Y)
{
    int lane = threadIdx.x & 63;
    int row = blockIdx.x * 4 + (threadIdx.x >> 6);
    const float4 v = *(const float4*)(X + (size_t)row * 256 + lane * 4);
    float s = v.x + v.y + v.z + v.w;
    float q = v.x * v.x + v.y * v.y + v.z * v.z + v.w * v.w;
#pragma unroll
    for (int o = 1; o < 64; o <<= 1) { s += __shfl_xor(s, o, 64); q += __shfl_xor(q, o, 64); }
    float mean = s * (1.f / 256.f);
    float var = q * (1.f / 256.f) - mean * mean;
    float inv = rsqrtf(var + 1e-5f);
    float4 gg = *(const float4*)(g + lane * 4);
    float4 bb = *(const float4*)(b2 + lane * 4);
    float4 o4;
    o4.x = (v.x - mean) * inv * gg.x + bb.x;
    o4.y = (v.y - mean) * inv * gg.y + bb.y;
    o4.z = (v.z - mean) * inv * gg.z + bb.z;
    o4.w = (v.w - mean) * inv * gg.w + bb.w;
    *(float4*)(Y + (size_t)row * 256 + lane * 4) = o4;
}

// mean over seq then dot with Wf + bf. one block per batch.
__global__ __launch_bounds__(256) void final_k(
    const float* __restrict__ H, const float* __restrict__ Wf,
    const float* __restrict__ bf, float* __restrict__ out)
{
    int b = blockIdx.x;
    int c = threadIdx.x;
    const float* p = H + (size_t)b * SEQ_LEN * 256 + c;
    float s = 0.f;
    for (int t = 0; t < SEQ_LEN; t++) s += p[t * 256];
    float v = s * (1.f / 1024.f) * Wf[c];
    int lane = c & 63;
#pragma unroll
    for (int o = 1; o < 64; o <<= 1) v += __shfl_xor(v, o, 64);
    __shared__ float red[4];
    if (lane == 0) red[c >> 6] = v;
    __syncthreads();
    if (c == 0) out[b] = red[0] + red[1] + red[2] + red[3] + bf[0];
}

extern "C" void kernel_launch(void* const* d_in, const int* in_sizes, int n_in,
                              void* d_out, int out_size, void* d_ws, size_t ws_size,
                              hipStream_t stream)
{
    const float* x      = (const float*)d_in[0];
    const float* Wp     = (const float*)d_in[1];
    const float* bp     = (const float*)d_in[2];
    const float* W_in   = (const float*)d_in[3];
    const float* conv_w = (const float*)d_in[4];
    const float* conv_b = (const float*)d_in[5];
    const float* W_x    = (const float*)d_in[6];
    const float* W_dt   = (const float*)d_in[7];
    const float* b_dt   = (const float*)d_in[8];
    const float* A_log  = (const float*)d_in[9];
    const float* Dp     = (const float*)d_in[10];
    const float* W_out  = (const float*)d_in[11];
    const float* ln_g   = (const float*)d_in[12];
    const float* ln_b   = (const float*)d_in[13];
    const float* Wf     = (const float*)d_in[14];
    const float* bf     = (const float*)d_in[15];

    float* ws = (float*)d_ws;
    float* bufXZ = ws;                             // 8192*1024 = 8388608
    float* bufXC = bufXZ + (size_t)ROWS * 1024;    // 8192*512
    float* bufDT = bufXC + (size_t)ROWS * 512;     // 8192*512
    float* bufXD = bufDT + (size_t)ROWS * 512;     // 8192*48
    float* bufH  = bufXD + (size_t)ROWS * 48;      // 8192*256
    float* bufO  = bufXC;                          // [ROWS][256] overlays dead xc

    dim3 blk(256);

    // h = x @ Wp^T + bp    (M=8192,N=256,K=64)
    gemm_bt<0><<<dim3(2, 64), blk, 0, stream>>>(x, Wp, bp, bufH,
                                                ROWS, DMODEL, 64, 64, 64, DMODEL);

    for (int l = 0; l < 4; ++l) {
        const float* Wi  = W_in   + (size_t)l * 2 * DINNER * DMODEL;
        const float* cw  = conv_w + (size_t)l * DINNER * 4;
        const float* cb  = conv_b + (size_t)l * DINNER;
        const float* Wx  = W_x    + (size_t)l * (DTRANK + 2 * DSTATE) * DINNER;
        const float* Wdt = W_dt   + (size_t)l * DINNER * DTRANK;
        const float* bdt = b_dt   + (size_t)l * DINNER;
        const float* Al  = A_log  + (size_t)l * DINNER * DSTATE;
        const float* Dl  = Dp     + (size_t)l * DINNER;
        const float* Wo  = W_out  + (size_t)l * DMODEL * DINNER;
        const float* lg  = ln_g   + (size_t)l * DMODEL;
        const float* lb  = ln_b   + (size_t)l * DMODEL;

        // xz = h @ W_in^T   (N=1024, K=256)
        gemm_bt<0><<<dim3(8, 64), blk, 0, stream>>>(bufH, Wi, nullptr, bufXZ,
                                                    ROWS, 1024, DMODEL, DMODEL, DMODEL, 1024);
        // conv + silu -> xc
        conv_silu_k<<<dim3(ROWS * DINNER / 256), blk, 0, stream>>>(bufXZ, cw, cb, bufXC);
        // x_dbl = xc @ W_x^T  (N=48, K=512)
        gemm_bt<0><<<dim3(1, 64), blk, 0, stream>>>(bufXC, Wx, nullptr, bufXD,
                                                    ROWS, 48, DINNER, DINNER, DINNER, 48);
        // dt = softplus(dtr @ W_dt^T + b_dt)  (N=512, K=16, lda=48)
        gemm_bt<1><<<dim3(4, 64), blk, 0, stream>>>(bufXD, Wdt, bdt, bufDT,
                                                    ROWS, DINNER, DTRANK, 48, DTRANK, DINNER);
        // chunked selective scan -> y*silu(z) into bufXZ cols 0..511
        scan_k<<<dim3(BATCH_N * DINNER), blk, 0, stream>>>(bufDT, bufXC, bufXD, bufXZ, Al, Dl);
        // out = y @ W_out^T  (N=256, K=512, lda=1024) -> bufO (overlays xc)
        gemm_bt<0><<<dim3(2, 64), blk, 0, stream>>>(bufXZ, Wo, nullptr, bufO,
                                                    ROWS, DMODEL, DINNER, 1024, DINNER, DMODEL);
        // layernorm -> bufH
        ln_k<<<dim3(ROWS / 4), blk, 0, stream>>>(bufO, lg, lb, bufH);
    }

    final_k<<<dim3(BATCH_N), blk, 0, stream>>>(bufH, Wf, bf, (float*)d_out);

    (void)in_sizes; (void)n_in; (void)out_size; (void)ws_size;
}

// Round 3
// 1455.068 us; speedup vs baseline: 2.8939x; 1.3847x over previous
//
#include <hip/hip_runtime.h>
#include <hip/hip_bf16.h>
#include <math.h>

#define SEQ_LEN 1024
#define BATCH_N 8
#define DMODEL 256
#define DINNER 512
#define DSTATE 16
#define DTRANK 16
#define ROWS (BATCH_N * SEQ_LEN)   // 8192
#define NCHUNK 32
#define CHUNK (SEQ_LEN / NCHUNK)   // 32
#define BD 8                       // d-channels per block

__device__ __forceinline__ float siluf(float x) { return x / (1.f + expf(-x)); }
__device__ __forceinline__ float softplusf(float x) {
    return fmaxf(x, 0.f) + log1pf(expf(-fabsf(x)));
}

// C[M,N] = act(A[M,K] @ B[N,K]^T + bias)
// 128x128 tile, 256 threads, 8x8 per thread (2x2 blocks of 4x4 at stride 64).
// M % 128 == 0, K % 16 == 0 assumed; N guarded.
template<int ACT>   // 0 = none, 1 = softplus
__global__ __launch_bounds__(256) void gemm_bt(
    const float* __restrict__ A, const float* __restrict__ B,
    const float* __restrict__ bias, float* __restrict__ C,
    int M, int N, int K, int lda, int ldb, int ldc)
{
    __shared__ float As[16][128];
    __shared__ float Bs[16][128];
    const int tid = threadIdx.x;
    const int bm = blockIdx.y * 128;
    const int bn = blockIdx.x * 128;
    const int tm = tid >> 4;      // 0..15
    const int tn = tid & 15;      // 0..15

    float acc[8][8];
#pragma unroll
    for (int i = 0; i < 8; i++)
#pragma unroll
        for (int j = 0; j < 8; j++) acc[i][j] = 0.f;

    for (int k0 = 0; k0 < K; k0 += 16) {
#pragma unroll
        for (int it = 0; it < 2; ++it) {
            int s = tid + it * 256;          // 0..511 float4-slots
            int row = s >> 2;                // 0..127
            int c4  = (s & 3) << 2;          // 0,4,8,12
            float4 va = *(const float4*)(A + (size_t)(bm + row) * lda + k0 + c4);
            As[c4 + 0][row] = va.x; As[c4 + 1][row] = va.y;
            As[c4 + 2][row] = va.z; As[c4 + 3][row] = va.w;
            float4 vb;
            if (bn + row < N)
                vb = *(const float4*)(B + (size_t)(bn + row) * ldb + k0 + c4);
            else
                vb = make_float4(0.f, 0.f, 0.f, 0.f);
            Bs[c4 + 0][row] = vb.x; Bs[c4 + 1][row] = vb.y;
            Bs[c4 + 2][row] = vb.z; Bs[c4 + 3][row] = vb.w;
        }
        __syncthreads();
#pragma unroll
        for (int k = 0; k < 16; k++) {
            float a[8], bb[8];
            *(float4*)&a[0]  = *(const float4*)&As[k][tm * 4];
            *(float4*)&a[4]  = *(const float4*)&As[k][tm * 4 + 64];
            *(float4*)&bb[0] = *(const float4*)&Bs[k][tn * 4];
            *(float4*)&bb[4] = *(const float4*)&Bs[k][tn * 4 + 64];
#pragma unroll
            for (int i = 0; i < 8; i++)
#pragma unroll
                for (int j = 0; j < 8; j++)
                    acc[i][j] = fmaf(a[i], bb[j], acc[i][j]);
        }
        __syncthreads();
    }

#pragma unroll
    for (int i = 0; i < 8; i++) {
        int r = bm + tm * 4 + ((i < 4) ? i : (60 + i));  // i>=4 -> +64
        float* crow = C + (size_t)r * ldc;
#pragma unroll
        for (int jj = 0; jj < 2; jj++) {
            int c = bn + tn * 4 + jj * 64;
            float v0 = acc[i][jj * 4 + 0], v1 = acc[i][jj * 4 + 1];
            float v2 = acc[i][jj * 4 + 2], v3 = acc[i][jj * 4 + 3];
            if (c + 3 < N) {
                if (bias) { v0 += bias[c]; v1 += bias[c + 1]; v2 += bias[c + 2]; v3 += bias[c + 3]; }
                if (ACT == 1) { v0 = softplusf(v0); v1 = softplusf(v1); v2 = softplusf(v2); v3 = softplusf(v3); }
                *(float4*)(crow + c) = make_float4(v0, v1, v2, v3);
            } else {
                float vv[4] = {v0, v1, v2, v3};
                for (int j = 0; j < 4; j++) {
                    if (c + j < N) {
                        float v = vv[j];
                        if (bias) v += bias[c + j];
                        if (ACT == 1) v = softplusf(v);
                        crow[c + j] = v;
                    }
                }
            }
        }
    }
}

// causal depthwise conv (k=4) + bias + silu.  xz: [ROWS][1024], xh = cols 0..511
__global__ __launch_bounds__(256) void conv_silu_k(
    const float* __restrict__ xz, const float* __restrict__ cw,
    const float* __restrict__ cb, float* __restrict__ xc)
{
    int idx = blockIdx.x * 256 + threadIdx.x;   // < ROWS*DINNER
    int d = idx & (DINNER - 1);
    int row = idx >> 9;
    int t = row & (SEQ_LEN - 1);
    float4 w = *(const float4*)(cw + d * 4);
    float acc = cb[d];
    const float* p = xz + (size_t)row * 1024 + d;
    if (t >= 3) acc = fmaf(p[-3 * 1024], w.x, acc);
    if (t >= 2) acc = fmaf(p[-2 * 1024], w.y, acc);
    if (t >= 1) acc = fmaf(p[-1 * 1024], w.z, acc);
    acc = fmaf(p[0], w.w, acc);
    xc[idx] = siluf(acc);
}

// Chunked selective scan, one thread per (b, d, chunk) carrying all 16 states.
// Block: 256 threads = 8 d-lanes x 32 chunks (whole sequence for 8 channels).
// Lane->d mapping keeps dt/xc/z/y accesses coalesced (32B per wave-quarter);
// paired blocks (same 16-d group) are swizzled to the same XCD for line reuse.
// Phase A: local scan (h0=0) -> P = exp(An*sum dt) and S per chunk, in LDS.
// Phase B: 128 threads do the 32-step inter-chunk combine (one per (d,n)).
// Phase C: re-scan with correct h0, y = sum_n h*C + D*xc, y *= silu(z).
__global__ __launch_bounds__(256) void scan_k(
    const float* __restrict__ dt,    // [ROWS][512]
    const float* __restrict__ xc,    // [ROWS][512]
    const float* __restrict__ xdbl,  // [ROWS][48]  (B at +16, C at +32)
    float* __restrict__ xz,          // [ROWS][1024]  z at +512, y out at col d
    const float* __restrict__ A_log, // [512][16]
    const float* __restrict__ Dp)    // [512]
{
    const int tid = threadIdx.x;
    const int dl  = tid & (BD - 1);      // 0..7
    const int ch  = tid >> 3;            // 0..31
    // XCD-pair swizzle: blocks P and P+256 handle adjacent 8-d halves of a
    // 16-d group and land on the same XCD (256 % 8 == 0).
    const int P2 = blockIdx.x & 255;
    const int e  = blockIdx.x >> 8;
    const int b  = P2 >> 5;                       // 0..7
    const int dg = ((P2 & 31) << 1) | e;          // 0..63
    const int d  = dg * BD + dl;

    __shared__ float ldsP[NCHUNK * BD * 16];   // 16 KB (reused as H0)
    __shared__ float ldsS[NCHUNK * BD * 16];   // 16 KB

    float An[16];
#pragma unroll
    for (int n = 0; n < 16; n++) An[n] = -expf(A_log[d * 16 + n]);

    const int t0 = b * SEQ_LEN + ch * CHUNK;
    const int base = (ch * BD + dl) * 16;

    // ---- Phase A ----
    float S[16];
#pragma unroll
    for (int n = 0; n < 16; n++) S[n] = 0.f;
    float sdt = 0.f;
#pragma unroll 2
    for (int t = 0; t < CHUNK; ++t) {
        const size_t row = (size_t)(t0 + t);
        float dtv = dt[row * 512 + d];
        float xcv = xc[row * 512 + d];
        float Bv[16];
        *(float4*)&Bv[0]  = *(const float4*)(xdbl + row * 48 + 16);
        *(float4*)&Bv[4]  = *(const float4*)(xdbl + row * 48 + 20);
        *(float4*)&Bv[8]  = *(const float4*)(xdbl + row * 48 + 24);
        *(float4*)&Bv[12] = *(const float4*)(xdbl + row * 48 + 28);
        sdt += dtv;
        float u = dtv * xcv;
#pragma unroll
        for (int n = 0; n < 16; n++)
            S[n] = fmaf(expf(dtv * An[n]), S[n], u * Bv[n]);
    }
#pragma unroll
    for (int n = 0; n < 16; n++) {
        ldsP[base + n] = expf(sdt * An[n]);
        ldsS[base + n] = S[n];
    }
    __syncthreads();

    // ---- Phase B: inter-chunk combine, one thread per (d,n) state ----
    if (tid < BD * 16) {
        const int dd = tid >> 4;
        const int nn = tid & 15;
        float h = 0.f;
#pragma unroll
        for (int c = 0; c < NCHUNK; ++c) {
            const int idx = (c * BD + dd) * 16 + nn;
            float Pv = ldsP[idx];
            float Sv = ldsS[idx];
            ldsP[idx] = h;                 // H0 overwrites P (already consumed)
            h = fmaf(Pv, h, Sv);
        }
    }
    __syncthreads();

    // ---- Phase C ----
    float h[16];
#pragma unroll
    for (int n = 0; n < 16; n++) h[n] = ldsP[base + n];
    const float Dd = Dp[d];
#pragma unroll 2
    for (int t = 0; t < CHUNK; ++t) {
        const size_t row = (size_t)(t0 + t);
        float dtv = dt[row * 512 + d];
        float xcv = xc[row * 512 + d];
        float Bv[16], Cv[16];
        *(float4*)&Bv[0]  = *(const float4*)(xdbl + row * 48 + 16);
        *(float4*)&Bv[4]  = *(const float4*)(xdbl + row * 48 + 20);
        *(float4*)&Bv[8]  = *(const float4*)(xdbl + row * 48 + 24);
        *(float4*)&Bv[12] = *(const float4*)(xdbl + row * 48 + 28);
        *(float4*)&Cv[0]  = *(const float4*)(xdbl + row * 48 + 32);
        *(float4*)&Cv[4]  = *(const float4*)(xdbl + row * 48 + 36);
        *(float4*)&Cv[8]  = *(const float4*)(xdbl + row * 48 + 40);
        *(float4*)&Cv[12] = *(const float4*)(xdbl + row * 48 + 44);
        float zv = xz[row * 1024 + 512 + d];
        float u = dtv * xcv;
        float y = 0.f;
#pragma unroll
        for (int n = 0; n < 16; n++) {
            float dA = expf(dtv * An[n]);
            h[n] = fmaf(dA, h[n], u * Bv[n]);
            y = fmaf(h[n], Cv[n], y);
        }
        y = fmaf(Dd, xcv, y);
        y *= siluf(zv);
        xz[row * 1024 + d] = y;
    }
}

// LayerNorm over 256 features; one wave per row, 4 rows per block.
__global__ __launch_bounds__(256) void ln_k(
    const float* __restrict__ X, const float* __restrict__ g,
    const float* __restrict__ b2, float* __restrict__ Y)
{
    int lane = threadIdx.x & 63;
    int row = blockIdx.x * 4 + (threadIdx.x >> 6);
    const float4 v = *(const float4*)(X + (size_t)row * 256 + lane * 4);
    float s = v.x + v.y + v.z + v.w;
    float q = v.x * v.x + v.y * v.y + v.z * v.z + v.w * v.w;
#pragma unroll
    for (int o = 1; o < 64; o <<= 1) { s += __shfl_xor(s, o, 64); q += __shfl_xor(q, o, 64); }
    float mean = s * (1.f / 256.f);
    float var = q * (1.f / 256.f) - mean * mean;
    float inv = rsqrtf(var + 1e-5f);
    float4 gg = *(const float4*)(g + lane * 4);
    float4 bb = *(const float4*)(b2 + lane * 4);
    float4 o4;
    o4.x = (v.x - mean) * inv * gg.x + bb.x;
    o4.y = (v.y - mean) * inv * gg.y + bb.y;
    o4.z = (v.z - mean) * inv * gg.z + bb.z;
    o4.w = (v.w - mean) * inv * gg.w + bb.w;
    *(float4*)(Y + (size_t)row * 256 + lane * 4) = o4;
}

// mean over seq then dot with Wf + bf. one block per batch.
__global__ __launch_bounds__(256) void final_k(
    const float* __restrict__ H, const float* __restrict__ Wf,
    const float* __restrict__ bf, float* __restrict__ out)
{
    int b = blockIdx.x;
    int c = threadIdx.x;
    const float* p = H + (size_t)b * SEQ_LEN * 256 + c;
    float s = 0.f;
    for (int t = 0; t < SEQ_LEN; t++) s += p[t * 256];
    float v = s * (1.f / 1024.f) * Wf[c];
    int lane = c & 63;
#pragma unroll
    for (int o = 1; o < 64; o <<= 1) v += __shfl_xor(v, o, 64);
    __shared__ float red[4];
    if (lane == 0) red[c >> 6] = v;
    __syncthreads();
    if (c == 0) out[b] = red[0] + red[1] + red[2] + red[3] + bf[0];
}

extern "C" void kernel_launch(void* const* d_in, const int* in_sizes, int n_in,
                              void* d_out, int out_size, void* d_ws, size_t ws_size,
                              hipStream_t stream)
{
    const float* x      = (const float*)d_in[0];
    const float* Wp     = (const float*)d_in[1];
    const float* bp     = (const float*)d_in[2];
    const float* W_in   = (const float*)d_in[3];
    const float* conv_w = (const float*)d_in[4];
    const float* conv_b = (const float*)d_in[5];
    const float* W_x    = (const float*)d_in[6];
    const float* W_dt   = (const float*)d_in[7];
    const float* b_dt   = (const float*)d_in[8];
    const float* A_log  = (const float*)d_in[9];
    const float* Dp     = (const float*)d_in[10];
    const float* W_out  = (const float*)d_in[11];
    const float* ln_g   = (const float*)d_in[12];
    const float* ln_b   = (const float*)d_in[13];
    const float* Wf     = (const float*)d_in[14];
    const float* bf     = (const float*)d_in[15];

    float* ws = (float*)d_ws;
    float* bufXZ = ws;                             // 8192*1024 = 8388608
    float* bufXC = bufXZ + (size_t)ROWS * 1024;    // 8192*512
    float* bufDT = bufXC + (size_t)ROWS * 512;     // 8192*512
    float* bufXD = bufDT + (size_t)ROWS * 512;     // 8192*48
    float* bufH  = bufXD + (size_t)ROWS * 48;      // 8192*256
    float* bufO  = bufXC;                          // [ROWS][256] overlays dead xc

    dim3 blk(256);

    // h = x @ Wp^T + bp    (M=8192,N=256,K=64)
    gemm_bt<0><<<dim3(2, 64), blk, 0, stream>>>(x, Wp, bp, bufH,
                                                ROWS, DMODEL, 64, 64, 64, DMODEL);

    for (int l = 0; l < 4; ++l) {
        const float* Wi  = W_in   + (size_t)l * 2 * DINNER * DMODEL;
        const float* cw  = conv_w + (size_t)l * DINNER * 4;
        const float* cb  = conv_b + (size_t)l * DINNER;
        const float* Wx  = W_x    + (size_t)l * (DTRANK + 2 * DSTATE) * DINNER;
        const float* Wdt = W_dt   + (size_t)l * DINNER * DTRANK;
        const float* bdt = b_dt   + (size_t)l * DINNER;
        const float* Al  = A_log  + (size_t)l * DINNER * DSTATE;
        const float* Dl  = Dp     + (size_t)l * DINNER;
        const float* Wo  = W_out  + (size_t)l * DMODEL * DINNER;
        const float* lg  = ln_g   + (size_t)l * DMODEL;
        const float* lb  = ln_b   + (size_t)l * DMODEL;

        // xz = h @ W_in^T   (N=1024, K=256)
        gemm_bt<0><<<dim3(8, 64), blk, 0, stream>>>(bufH, Wi, nullptr, bufXZ,
                                                    ROWS, 1024, DMODEL, DMODEL, DMODEL, 1024);
        // conv + silu -> xc
        conv_silu_k<<<dim3(ROWS * DINNER / 256), blk, 0, stream>>>(bufXZ, cw, cb, bufXC);
        // x_dbl = xc @ W_x^T  (N=48, K=512)
        gemm_bt<0><<<dim3(1, 64), blk, 0, stream>>>(bufXC, Wx, nullptr, bufXD,
                                                    ROWS, 48, DINNER, DINNER, DINNER, 48);
        // dt = softplus(dtr @ W_dt^T + b_dt)  (N=512, K=16, lda=48)
        gemm_bt<1><<<dim3(4, 64), blk, 0, stream>>>(bufXD, Wdt, bdt, bufDT,
                                                    ROWS, DINNER, DTRANK, 48, DTRANK, DINNER);
        // chunked selective scan -> y*silu(z) into bufXZ cols 0..511
        scan_k<<<dim3(512), blk, 0, stream>>>(bufDT, bufXC, bufXD, bufXZ, Al, Dl);
        // out = y @ W_out^T  (N=256, K=512, lda=1024) -> bufO (overlays xc)
        gemm_bt<0><<<dim3(2, 64), blk, 0, stream>>>(bufXZ, Wo, nullptr, bufO,
                                                    ROWS, DMODEL, DINNER, 1024, DINNER, DMODEL);
        // layernorm -> bufH
        ln_k<<<dim3(ROWS / 4), blk, 0, stream>>>(bufO, lg, lb, bufH);
    }

    final_k<<<dim3(BATCH_N), blk, 0, stream>>>(bufH, Wf, bf, (float*)d_out);

    (void)in_sizes; (void)n_in; (void)out_size; (void)ws_size;
}

// Round 4
// 1360.472 us; speedup vs baseline: 3.0952x; 1.0695x over previous
//
#include <hip/hip_runtime.h>
#include <hip/hip_bf16.h>
#include <math.h>

#define SEQ_LEN 1024
#define BATCH_N 8
#define DMODEL 256
#define DINNER 512
#define DSTATE 16
#define DTRANK 16
#define ROWS (BATCH_N * SEQ_LEN)   // 8192
#define NCHUNK 32
#define CHUNK (SEQ_LEN / NCHUNK)   // 32
#define BD 8                       // d-channels per block (scan)
#define LSTR 40                    // LDS row stride in ushorts (16B-aligned, depadded)

typedef short bf16x8 __attribute__((ext_vector_type(8)));
typedef float f32x4 __attribute__((ext_vector_type(4)));

__device__ __forceinline__ float siluf(float x) { return x / (1.f + expf(-x)); }
__device__ __forceinline__ float softplusf(float x) {
    return fmaxf(x, 0.f) + log1pf(expf(-fabsf(x)));
}

__device__ __forceinline__ unsigned short bf16_rne(float x) {
    unsigned u = __builtin_bit_cast(unsigned, x);
    return (unsigned short)((u + 0x7FFFu + ((u >> 16) & 1u)) >> 16);
}
// split x -> hi (bf16 rne) + lo (bf16 rne of residual)
__device__ __forceinline__ void cvt_hl(float x, unsigned short& h, unsigned short& l) {
    unsigned u = __builtin_bit_cast(unsigned, x);
    unsigned hb = (u + 0x7FFFu + ((u >> 16) & 1u)) >> 16;
    h = (unsigned short)hb;
    float hf = __builtin_bit_cast(float, hb << 16);
    l = bf16_rne(x - hf);
}

// ---------------------------------------------------------------------------
// MFMA GEMM: C[M,N] = A[M,K] @ B[N,K]^T (+bias), fp32 in/out.
// Split-precision: A,B -> bf16 hi+lo; acc += Ah*Bh + Ah*Bl + Al*Bh (fp32 acc).
// 128x128 tile, 256 thr = 4 waves in 2x2; each wave 4x4 frags of 16x16x32.
// M % 128 == 0, K % 32 == 0 assumed; N guarded (for N=48 case).
// ---------------------------------------------------------------------------
__global__ __launch_bounds__(256) void gemm_mfma(
    const float* __restrict__ A, const float* __restrict__ B,
    const float* __restrict__ bias, float* __restrict__ C,
    int M, int N, int K, int lda, int ldb, int ldc)
{
    __shared__ unsigned short lds[4 * 128 * LSTR];   // Ahi Alo Bhi Blo = 40 KB
    unsigned short* Ahi = lds;
    unsigned short* Alo = lds + 128 * LSTR;
    unsigned short* Bhi = lds + 2 * 128 * LSTR;
    unsigned short* Blo = lds + 3 * 128 * LSTR;

    const int tid  = threadIdx.x;
    const int bm   = blockIdx.y * 128, bn = blockIdx.x * 128;
    const int wave = tid >> 6, lane = tid & 63;
    const int wm   = (wave >> 1) * 64, wn = (wave & 1) * 64;
    const int fr   = lane & 15;    // frag row (A-m / B-n)
    const int quad = lane >> 4;    // k-group

    f32x4 acc[4][4];
#pragma unroll
    for (int i = 0; i < 4; i++)
#pragma unroll
        for (int j = 0; j < 4; j++) acc[i][j] = (f32x4){0.f, 0.f, 0.f, 0.f};

    const int srow = tid >> 1;            // 0..127
    const int sk   = (tid & 1) * 16;      // 0 or 16
    const bool bvalid = (bn + srow) < N;
    const float* pa = A + (size_t)(bm + srow) * lda + sk;
    const float* pb = B + (size_t)(bn + srow) * ldb + sk;
    unsigned short* wah = Ahi + srow * LSTR + sk;
    unsigned short* wal = Alo + srow * LSTR + sk;
    unsigned short* wbh = Bhi + srow * LSTR + sk;
    unsigned short* wbl = Blo + srow * LSTR + sk;

    for (int k0 = 0; k0 < K; k0 += 32) {
#pragma unroll
        for (int j = 0; j < 16; j += 4) {
            float4 va = *(const float4*)(pa + k0 + j);
            ushort4 h, l;
            cvt_hl(va.x, h.x, l.x); cvt_hl(va.y, h.y, l.y);
            cvt_hl(va.z, h.z, l.z); cvt_hl(va.w, h.w, l.w);
            *(ushort4*)(wah + j) = h;
            *(ushort4*)(wal + j) = l;
            float4 vb = bvalid ? *(const float4*)(pb + k0 + j)
                               : make_float4(0.f, 0.f, 0.f, 0.f);
            cvt_hl(vb.x, h.x, l.x); cvt_hl(vb.y, h.y, l.y);
            cvt_hl(vb.z, h.z, l.z); cvt_hl(vb.w, h.w, l.w);
            *(ushort4*)(wbh + j) = h;
            *(ushort4*)(wbl + j) = l;
        }
        __syncthreads();

        bf16x8 ah[4], al[4], bh[4], bl[4];
#pragma unroll
        for (int i = 0; i < 4; i++) {
            const int ra = (wm + 16 * i + fr) * LSTR + quad * 8;
            const int rb = (wn + 16 * i + fr) * LSTR + quad * 8;
            ah[i] = *(const bf16x8*)(Ahi + ra);
            al[i] = *(const bf16x8*)(Alo + ra);
            bh[i] = *(const bf16x8*)(Bhi + rb);
            bl[i] = *(const bf16x8*)(Blo + rb);
        }
#pragma unroll
        for (int i = 0; i < 4; i++)
#pragma unroll
            for (int j = 0; j < 4; j++) {
                acc[i][j] = __builtin_amdgcn_mfma_f32_16x16x32_bf16(ah[i], bh[j], acc[i][j], 0, 0, 0);
                acc[i][j] = __builtin_amdgcn_mfma_f32_16x16x32_bf16(ah[i], bl[j], acc[i][j], 0, 0, 0);
                acc[i][j] = __builtin_amdgcn_mfma_f32_16x16x32_bf16(al[i], bh[j], acc[i][j], 0, 0, 0);
            }
        __syncthreads();
    }

    // C/D layout (m89-verified): row = quad*4 + reg, col = fr within 16x16 frag
#pragma unroll
    for (int i = 0; i < 4; i++) {
        const int r0 = bm + wm + 16 * i + quad * 4;
#pragma unroll
        for (int reg = 0; reg < 4; reg++) {
            float* crow = C + (size_t)(r0 + reg) * ldc;
#pragma unroll
            for (int j = 0; j < 4; j++) {
                const int col = bn + wn + 16 * j + fr;
                if (col < N) {
                    float v = acc[i][j][reg];
                    if (bias) v += bias[col];
                    crow[col] = v;
                }
            }
        }
    }
}

// ---------------------------------------------------------------------------
// fp32 vector GEMM (kept for the tiny K=16 dt projection only)
// ---------------------------------------------------------------------------
template<int ACT>   // 0 = none, 1 = softplus
__global__ __launch_bounds__(256) void gemm_bt(
    const float* __restrict__ A, const float* __restrict__ B,
    const float* __restrict__ bias, float* __restrict__ C,
    int M, int N, int K, int lda, int ldb, int ldc)
{
    __shared__ float As[16][128];
    __shared__ float Bs[16][128];
    const int tid = threadIdx.x;
    const int bm = blockIdx.y * 128;
    const int bn = blockIdx.x * 128;
    const int tm = tid >> 4;
    const int tn = tid & 15;

    float acc[8][8];
#pragma unroll
    for (int i = 0; i < 8; i++)
#pragma unroll
        for (int j = 0; j < 8; j++) acc[i][j] = 0.f;

    for (int k0 = 0; k0 < K; k0 += 16) {
#pragma unroll
        for (int it = 0; it < 2; ++it) {
            int s = tid + it * 256;
            int row = s >> 2;
            int c4  = (s & 3) << 2;
            float4 va = *(const float4*)(A + (size_t)(bm + row) * lda + k0 + c4);
            As[c4 + 0][row] = va.x; As[c4 + 1][row] = va.y;
            As[c4 + 2][row] = va.z; As[c4 + 3][row] = va.w;
            float4 vb;
            if (bn + row < N)
                vb = *(const float4*)(B + (size_t)(bn + row) * ldb + k0 + c4);
            else
                vb = make_float4(0.f, 0.f, 0.f, 0.f);
            Bs[c4 + 0][row] = vb.x; Bs[c4 + 1][row] = vb.y;
            Bs[c4 + 2][row] = vb.z; Bs[c4 + 3][row] = vb.w;
        }
        __syncthreads();
#pragma unroll
        for (int k = 0; k < 16; k++) {
            float a[8], bb[8];
            *(float4*)&a[0]  = *(const float4*)&As[k][tm * 4];
            *(float4*)&a[4]  = *(const float4*)&As[k][tm * 4 + 64];
            *(float4*)&bb[0] = *(const float4*)&Bs[k][tn * 4];
            *(float4*)&bb[4] = *(const float4*)&Bs[k][tn * 4 + 64];
#pragma unroll
            for (int i = 0; i < 8; i++)
#pragma unroll
                for (int j = 0; j < 8; j++)
                    acc[i][j] = fmaf(a[i], bb[j], acc[i][j]);
        }
        __syncthreads();
    }

#pragma unroll
    for (int i = 0; i < 8; i++) {
        int r = bm + tm * 4 + ((i < 4) ? i : (60 + i));
        float* crow = C + (size_t)r * ldc;
#pragma unroll
        for (int jj = 0; jj < 2; jj++) {
            int c = bn + tn * 4 + jj * 64;
            float v0 = acc[i][jj * 4 + 0], v1 = acc[i][jj * 4 + 1];
            float v2 = acc[i][jj * 4 + 2], v3 = acc[i][jj * 4 + 3];
            if (c + 3 < N) {
                if (bias) { v0 += bias[c]; v1 += bias[c + 1]; v2 += bias[c + 2]; v3 += bias[c + 3]; }
                if (ACT == 1) { v0 = softplusf(v0); v1 = softplusf(v1); v2 = softplusf(v2); v3 = softplusf(v3); }
                *(float4*)(crow + c) = make_float4(v0, v1, v2, v3);
            } else {
                float vv[4] = {v0, v1, v2, v3};
                for (int j = 0; j < 4; j++) {
                    if (c + j < N) {
                        float v = vv[j];
                        if (bias) v += bias[c + j];
                        if (ACT == 1) v = softplusf(v);
                        crow[c + j] = v;
                    }
                }
            }
        }
    }
}

// causal depthwise conv (k=4) + bias + silu.  xz: [ROWS][1024], xh = cols 0..511
__global__ __launch_bounds__(256) void conv_silu_k(
    const float* __restrict__ xz, const float* __restrict__ cw,
    const float* __restrict__ cb, float* __restrict__ xc)
{
    int idx = blockIdx.x * 256 + threadIdx.x;
    int d = idx & (DINNER - 1);
    int row = idx >> 9;
    int t = row & (SEQ_LEN - 1);
    float4 w = *(const float4*)(cw + d * 4);
    float acc = cb[d];
    const float* p = xz + (size_t)row * 1024 + d;
    if (t >= 3) acc = fmaf(p[-3 * 1024], w.x, acc);
    if (t >= 2) acc = fmaf(p[-2 * 1024], w.y, acc);
    if (t >= 1) acc = fmaf(p[-1 * 1024], w.z, acc);
    acc = fmaf(p[0], w.w, acc);
    xc[idx] = siluf(acc);
}

// Chunked selective scan, one thread per (b, d, chunk) carrying all 16 states.
__global__ __launch_bounds__(256) void scan_k(
    const float* __restrict__ dt,    // [ROWS][512]
    const float* __restrict__ xc,    // [ROWS][512]
    const float* __restrict__ xdbl,  // [ROWS][48]  (B at +16, C at +32)
    float* __restrict__ xz,          // [ROWS][1024]  z at +512, y out at col d
    const float* __restrict__ A_log, // [512][16]
    const float* __restrict__ Dp)    // [512]
{
    const int tid = threadIdx.x;
    const int dl  = tid & (BD - 1);
    const int ch  = tid >> 3;
    const int P2 = blockIdx.x & 255;
    const int e  = blockIdx.x >> 8;
    const int b  = P2 >> 5;
    const int dg = ((P2 & 31) << 1) | e;
    const int d  = dg * BD + dl;

    __shared__ float ldsP[NCHUNK * BD * 16];
    __shared__ float ldsS[NCHUNK * BD * 16];

    float An[16];
#pragma unroll
    for (int n = 0; n < 16; n++) An[n] = -expf(A_log[d * 16 + n]);

    const int t0 = b * SEQ_LEN + ch * CHUNK;
    const int base = (ch * BD + dl) * 16;

    float S[16];
#pragma unroll
    for (int n = 0; n < 16; n++) S[n] = 0.f;
    float sdt = 0.f;
#pragma unroll 2
    for (int t = 0; t < CHUNK; ++t) {
        const size_t row = (size_t)(t0 + t);
        float dtv = dt[row * 512 + d];
        float xcv = xc[row * 512 + d];
        float Bv[16];
        *(float4*)&Bv[0]  = *(const float4*)(xdbl + row * 48 + 16);
        *(float4*)&Bv[4]  = *(const float4*)(xdbl + row * 48 + 20);
        *(float4*)&Bv[8]  = *(const float4*)(xdbl + row * 48 + 24);
        *(float4*)&Bv[12] = *(const float4*)(xdbl + row * 48 + 28);
        sdt += dtv;
        float u = dtv * xcv;
#pragma unroll
        for (int n = 0; n < 16; n++)
            S[n] = fmaf(expf(dtv * An[n]), S[n], u * Bv[n]);
    }
#pragma unroll
    for (int n = 0; n < 16; n++) {
        ldsP[base + n] = expf(sdt * An[n]);
        ldsS[base + n] = S[n];
    }
    __syncthreads();

    if (tid < BD * 16) {
        const int dd = tid >> 4;
        const int nn = tid & 15;
        float h = 0.f;
#pragma unroll
        for (int c = 0; c < NCHUNK; ++c) {
            const int idx = (c * BD + dd) * 16 + nn;
            float Pv = ldsP[idx];
            float Sv = ldsS[idx];
            ldsP[idx] = h;
            h = fmaf(Pv, h, Sv);
        }
    }
    __syncthreads();

    float h[16];
#pragma unroll
    for (int n = 0; n < 16; n++) h[n] = ldsP[base + n];
    const float Dd = Dp[d];
#pragma unroll 2
    for (int t = 0; t < CHUNK; ++t) {
        const size_t row = (size_t)(t0 + t);
        float dtv = dt[row * 512 + d];
        float xcv = xc[row * 512 + d];
        float Bv[16], Cv[16];
        *(float4*)&Bv[0]  = *(const float4*)(xdbl + row * 48 + 16);
        *(float4*)&Bv[4]  = *(const float4*)(xdbl + row * 48 + 20);
        *(float4*)&Bv[8]  = *(const float4*)(xdbl + row * 48 + 24);
        *(float4*)&Bv[12] = *(const float4*)(xdbl + row * 48 + 28);
        *(float4*)&Cv[0]  = *(const float4*)(xdbl + row * 48 + 32);
        *(float4*)&Cv[4]  = *(const float4*)(xdbl + row * 48 + 36);
        *(float4*)&Cv[8]  = *(const float4*)(xdbl + row * 48 + 40);
        *(float4*)&Cv[12] = *(const float4*)(xdbl + row * 48 + 44);
        float zv = xz[row * 1024 + 512 + d];
        float u = dtv * xcv;
        float y = 0.f;
#pragma unroll
        for (int n = 0; n < 16; n++) {
            float dA = expf(dtv * An[n]);
            h[n] = fmaf(dA, h[n], u * Bv[n]);
            y = fmaf(h[n], Cv[n], y);
        }
        y = fmaf(Dd, xcv, y);
        y *= siluf(zv);
        xz[row * 1024 + d] = y;
    }
}

// LayerNorm over 256 features; one wave per row, 4 rows per block.
__global__ __launch_bounds__(256) void ln_k(
    const float* __restrict__ X, const float* __restrict__ g,
    const float* __restrict__ b2, float* __restrict__ Y)
{
    int lane = threadIdx.x & 63;
    int row = blockIdx.x * 4 + (threadIdx.x >> 6);
    const float4 v = *(const float4*)(X + (size_t)row * 256 + lane * 4);
    float s = v.x + v.y + v.z + v.w;
    float q = v.x * v.x + v.y * v.y + v.z * v.z + v.w * v.w;
#pragma unroll
    for (int o = 1; o < 64; o <<= 1) { s += __shfl_xor(s, o, 64); q += __shfl_xor(q, o, 64); }
    float mean = s * (1.f / 256.f);
    float var = q * (1.f / 256.f) - mean * mean;
    float inv = rsqrtf(var + 1e-5f);
    float4 gg = *(const float4*)(g + lane * 4);
    float4 bb = *(const float4*)(b2 + lane * 4);
    float4 o4;
    o4.x = (v.x - mean) * inv * gg.x + bb.x;
    o4.y = (v.y - mean) * inv * gg.y + bb.y;
    o4.z = (v.z - mean) * inv * gg.z + bb.z;
    o4.w = (v.w - mean) * inv * gg.w + bb.w;
    *(float4*)(Y + (size_t)row * 256 + lane * 4) = o4;
}

// mean over seq then dot with Wf + bf. one block per batch.
__global__ __launch_bounds__(256) void final_k(
    const float* __restrict__ H, const float* __restrict__ Wf,
    const float* __restrict__ bf, float* __restrict__ out)
{
    int b = blockIdx.x;
    int c = threadIdx.x;
    const float* p = H + (size_t)b * SEQ_LEN * 256 + c;
    float s = 0.f;
    for (int t = 0; t < SEQ_LEN; t++) s += p[t * 256];
    float v = s * (1.f / 1024.f) * Wf[c];
    int lane = c & 63;
#pragma unroll
    for (int o = 1; o < 64; o <<= 1) v += __shfl_xor(v, o, 64);
    __shared__ float red[4];
    if (lane == 0) red[c >> 6] = v;
    __syncthreads();
    if (c == 0) out[b] = red[0] + red[1] + red[2] + red[3] + bf[0];
}

extern "C" void kernel_launch(void* const* d_in, const int* in_sizes, int n_in,
                              void* d_out, int out_size, void* d_ws, size_t ws_size,
                              hipStream_t stream)
{
    const float* x      = (const float*)d_in[0];
    const float* Wp     = (const float*)d_in[1];
    const float* bp     = (const float*)d_in[2];
    const float* W_in   = (const float*)d_in[3];
    const float* conv_w = (const float*)d_in[4];
    const float* conv_b = (const float*)d_in[5];
    const float* W_x    = (const float*)d_in[6];
    const float* W_dt   = (const float*)d_in[7];
    const float* b_dt   = (const float*)d_in[8];
    const float* A_log  = (const float*)d_in[9];
    const float* Dp     = (const float*)d_in[10];
    const float* W_out  = (const float*)d_in[11];
    const float* ln_g   = (const float*)d_in[12];
    const float* ln_b   = (const float*)d_in[13];
    const float* Wf     = (const float*)d_in[14];
    const float* bf     = (const float*)d_in[15];

    float* ws = (float*)d_ws;
    float* bufXZ = ws;                             // 8192*1024
    float* bufXC = bufXZ + (size_t)ROWS * 1024;    // 8192*512
    float* bufDT = bufXC + (size_t)ROWS * 512;     // 8192*512
    float* bufXD = bufDT + (size_t)ROWS * 512;     // 8192*48
    float* bufH  = bufXD + (size_t)ROWS * 48;      // 8192*256
    float* bufO  = bufXC;                          // [ROWS][256] overlays dead xc

    dim3 blk(256);

    // h = x @ Wp^T + bp    (M=8192,N=256,K=64)
    gemm_mfma<<<dim3(2, 64), blk, 0, stream>>>(x, Wp, bp, bufH,
                                               ROWS, DMODEL, 64, 64, 64, DMODEL);

    for (int l = 0; l < 4; ++l) {
        const float* Wi  = W_in   + (size_t)l * 2 * DINNER * DMODEL;
        const float* cw  = conv_w + (size_t)l * DINNER * 4;
        const float* cb  = conv_b + (size_t)l * DINNER;
        const float* Wx  = W_x    + (size_t)l * (DTRANK + 2 * DSTATE) * DINNER;
        const float* Wdt = W_dt   + (size_t)l * DINNER * DTRANK;
        const float* bdt = b_dt   + (size_t)l * DINNER;
        const float* Al  = A_log  + (size_t)l * DINNER * DSTATE;
        const float* Dl  = Dp     + (size_t)l * DINNER;
        const float* Wo  = W_out  + (size_t)l * DMODEL * DINNER;
        const float* lg  = ln_g   + (size_t)l * DMODEL;
        const float* lb  = ln_b   + (size_t)l * DMODEL;

        // xz = h @ W_in^T   (N=1024, K=256)
        gemm_mfma<<<dim3(8, 64), blk, 0, stream>>>(bufH, Wi, nullptr, bufXZ,
                                                   ROWS, 1024, DMODEL, DMODEL, DMODEL, 1024);
        // conv + silu -> xc
        conv_silu_k<<<dim3(ROWS * DINNER / 256), blk, 0, stream>>>(bufXZ, cw, cb, bufXC);
        // x_dbl = xc @ W_x^T  (N=48, K=512)
        gemm_mfma<<<dim3(1, 64), blk, 0, stream>>>(bufXC, Wx, nullptr, bufXD,
                                                   ROWS, 48, DINNER, DINNER, DINNER, 48);
        // dt = softplus(dtr @ W_dt^T + b_dt)  (N=512, K=16, lda=48)
        gemm_bt<1><<<dim3(4, 64), blk, 0, stream>>>(bufXD, Wdt, bdt, bufDT,
                                                    ROWS, DINNER, DTRANK, 48, DTRANK, DINNER);
        // chunked selective scan -> y*silu(z) into bufXZ cols 0..511
        scan_k<<<dim3(512), blk, 0, stream>>>(bufDT, bufXC, bufXD, bufXZ, Al, Dl);
        // out = y @ W_out^T  (N=256, K=512, lda=1024) -> bufO (overlays xc)
        gemm_mfma<<<dim3(2, 64), blk, 0, stream>>>(bufXZ, Wo, nullptr, bufO,
                                                   ROWS, DMODEL, DINNER, 1024, DINNER, DMODEL);
        // layernorm -> bufH
        ln_k<<<dim3(ROWS / 4), blk, 0, stream>>>(bufO, lg, lb, bufH);
    }

    final_k<<<dim3(BATCH_N), blk, 0, stream>>>(bufH, Wf, bf, (float*)d_out);

    (void)in_sizes; (void)n_in; (void)out_size; (void)ws_size;
}

// Round 5
// 849.255 us; speedup vs baseline: 4.9583x; 1.6020x over previous
//
#include <hip/hip_runtime.h>
#include <hip/hip_bf16.h>
#include <math.h>

#define SEQ_LEN 1024
#define BATCH_N 8
#define DMODEL 256
#define DINNER 512
#define DSTATE 16
#define DTRANK 16
#define ROWS (BATCH_N * SEQ_LEN)   // 8192
#define NCHUNK 64
#define CHUNK (SEQ_LEN / NCHUNK)   // 16
#define BD 8                       // d-channels per block (scan)
#define LSTR 40                    // LDS row stride in ushorts (gemm staging)

typedef short bf16x8 __attribute__((ext_vector_type(8)));
typedef float f32x4 __attribute__((ext_vector_type(4)));

__device__ __forceinline__ float siluf(float x) { return x / (1.f + expf(-x)); }
__device__ __forceinline__ float softplusf(float x) {
    return fmaxf(x, 0.f) + log1pf(expf(-fabsf(x)));
}

__device__ __forceinline__ unsigned short bf16_rne(float x) {
    unsigned u = __builtin_bit_cast(unsigned, x);
    return (unsigned short)((u + 0x7FFFu + ((u >> 16) & 1u)) >> 16);
}
// split x -> hi (bf16 rne) + lo (bf16 rne of residual)
__device__ __forceinline__ void cvt_hl(float x, unsigned short& h, unsigned short& l) {
    unsigned u = __builtin_bit_cast(unsigned, x);
    unsigned hb = (u + 0x7FFFu + ((u >> 16) & 1u)) >> 16;
    h = (unsigned short)hb;
    float hf = __builtin_bit_cast(float, hb << 16);
    l = bf16_rne(x - hf);
}

// ---------------------------------------------------------------------------
// MFMA GEMM: C[M,N] = A[M,K] @ B[N,K]^T (+bias), fp32 in/out.
// Split-precision: A,B -> bf16 hi+lo; acc += Ah*Bh + Ah*Bl + Al*Bh (fp32 acc).
// 128x128 tile, 256 thr = 4 waves in 2x2; each wave 4x4 frags of 16x16x32.
// M % 128 == 0, K % 32 == 0 assumed; N guarded (for N=48 case).
// ---------------------------------------------------------------------------
__global__ __launch_bounds__(256) void gemm_mfma(
    const float* __restrict__ A, const float* __restrict__ B,
    const float* __restrict__ bias, float* __restrict__ C,
    int M, int N, int K, int lda, int ldb, int ldc)
{
    __shared__ unsigned short lds[4 * 128 * LSTR];   // Ahi Alo Bhi Blo = 40 KB
    unsigned short* Ahi = lds;
    unsigned short* Alo = lds + 128 * LSTR;
    unsigned short* Bhi = lds + 2 * 128 * LSTR;
    unsigned short* Blo = lds + 3 * 128 * LSTR;

    const int tid  = threadIdx.x;
    const int bm   = blockIdx.y * 128, bn = blockIdx.x * 128;
    const int wave = tid >> 6, lane = tid & 63;
    const int wm   = (wave >> 1) * 64, wn = (wave & 1) * 64;
    const int fr   = lane & 15;    // frag row (A-m / B-n)
    const int quad = lane >> 4;    // k-group

    f32x4 acc[4][4];
#pragma unroll
    for (int i = 0; i < 4; i++)
#pragma unroll
        for (int j = 0; j < 4; j++) acc[i][j] = (f32x4){0.f, 0.f, 0.f, 0.f};

    const int srow = tid >> 1;            // 0..127
    const int sk   = (tid & 1) * 16;      // 0 or 16
    const bool bvalid = (bn + srow) < N;
    const float* pa = A + (size_t)(bm + srow) * lda + sk;
    const float* pb = B + (size_t)(bn + srow) * ldb + sk;
    unsigned short* wah = Ahi + srow * LSTR + sk;
    unsigned short* wal = Alo + srow * LSTR + sk;
    unsigned short* wbh = Bhi + srow * LSTR + sk;
    unsigned short* wbl = Blo + srow * LSTR + sk;

    for (int k0 = 0; k0 < K; k0 += 32) {
#pragma unroll
        for (int j = 0; j < 16; j += 4) {
            float4 va = *(const float4*)(pa + k0 + j);
            ushort4 h, l;
            cvt_hl(va.x, h.x, l.x); cvt_hl(va.y, h.y, l.y);
            cvt_hl(va.z, h.z, l.z); cvt_hl(va.w, h.w, l.w);
            *(ushort4*)(wah + j) = h;
            *(ushort4*)(wal + j) = l;
            float4 vb = bvalid ? *(const float4*)(pb + k0 + j)
                               : make_float4(0.f, 0.f, 0.f, 0.f);
            cvt_hl(vb.x, h.x, l.x); cvt_hl(vb.y, h.y, l.y);
            cvt_hl(vb.z, h.z, l.z); cvt_hl(vb.w, h.w, l.w);
            *(ushort4*)(wbh + j) = h;
            *(ushort4*)(wbl + j) = l;
        }
        __syncthreads();

        bf16x8 ah[4], al[4], bh[4], bl[4];
#pragma unroll
        for (int i = 0; i < 4; i++) {
            const int ra = (wm + 16 * i + fr) * LSTR + quad * 8;
            const int rb = (wn + 16 * i + fr) * LSTR + quad * 8;
            ah[i] = *(const bf16x8*)(Ahi + ra);
            al[i] = *(const bf16x8*)(Alo + ra);
            bh[i] = *(const bf16x8*)(Bhi + rb);
            bl[i] = *(const bf16x8*)(Blo + rb);
        }
#pragma unroll
        for (int i = 0; i < 4; i++)
#pragma unroll
            for (int j = 0; j < 4; j++) {
                acc[i][j] = __builtin_amdgcn_mfma_f32_16x16x32_bf16(ah[i], bh[j], acc[i][j], 0, 0, 0);
                acc[i][j] = __builtin_amdgcn_mfma_f32_16x16x32_bf16(ah[i], bl[j], acc[i][j], 0, 0, 0);
                acc[i][j] = __builtin_amdgcn_mfma_f32_16x16x32_bf16(al[i], bh[j], acc[i][j], 0, 0, 0);
            }
        __syncthreads();
    }

    // C/D layout (m89-verified): row = quad*4 + reg, col = fr within 16x16 frag
#pragma unroll
    for (int i = 0; i < 4; i++) {
        const int r0 = bm + wm + 16 * i + quad * 4;
#pragma unroll
        for (int reg = 0; reg < 4; reg++) {
            float* crow = C + (size_t)(r0 + reg) * ldc;
#pragma unroll
            for (int j = 0; j < 4; j++) {
                const int col = bn + wn + 16 * j + fr;
                if (col < N) {
                    float v = acc[i][j][reg];
                    if (bias) v += bias[col];
                    crow[col] = v;
                }
            }
        }
    }
}

// causal depthwise conv (k=4) + bias + silu.  xz: [ROWS][1024], xh = cols 0..511
__global__ __launch_bounds__(256) void conv_silu_k(
    const float* __restrict__ xz, const float* __restrict__ cw,
    const float* __restrict__ cb, float* __restrict__ xc)
{
    int idx = blockIdx.x * 256 + threadIdx.x;
    int d = idx & (DINNER - 1);
    int row = idx >> 9;
    int t = row & (SEQ_LEN - 1);
    float4 w = *(const float4*)(cw + d * 4);
    float acc = cb[d];
    const float* p = xz + (size_t)row * 1024 + d;
    if (t >= 3) acc = fmaf(p[-3 * 1024], w.x, acc);
    if (t >= 2) acc = fmaf(p[-2 * 1024], w.y, acc);
    if (t >= 1) acc = fmaf(p[-1 * 1024], w.z, acc);
    acc = fmaf(p[0], w.w, acc);
    xc[idx] = siluf(acc);
}

// ---------------------------------------------------------------------------
// Chunked selective scan with fused dt-projection.
// One thread per (b, d, chunk) carrying all 16 n-states in registers.
// Block: 512 threads = 8 d-lanes x 64 chunks (whole sequence for 8 channels).
// dt[row,d] = softplus(dot16(xdbl[row,0:16], Wdt[d,:]) + bdt[d]) computed
// on the fly (the dtr float4s share cache lines with the B/C loads).
// dA_n = exp(dt*An[n]); A_log = log(1..16) broadcast => An = -(n+1), so
// dA_n = exp(-dt)^(n+1): 1 exp + 15 muls (log-depth) instead of 16 exps.
// Guarded by a structural check with generic exp2 fallback (uniform branch).
// ---------------------------------------------------------------------------
__global__ __launch_bounds__(512, 4) void scan_k(
    const float* __restrict__ xc,    // [ROWS][512]
    const float* __restrict__ xdbl,  // [ROWS][48]  (dtr at 0, B at +16, C at +32)
    float* __restrict__ xz,          // [ROWS][1024]  z at +512, y out at col d
    const float* __restrict__ Wdt,   // [512][16]
    const float* __restrict__ bdt,   // [512]
    const float* __restrict__ A_log, // [512][16]
    const float* __restrict__ Dp)    // [512]
{
    const int tid = threadIdx.x;
    const int dl  = tid & (BD - 1);      // 0..7
    const int ch  = tid >> 3;            // 0..63
    // XCD-pair swizzle: blocks P2 and P2+256 are adjacent 8-d halves of a
    // 16-d group and land on the same XCD (256 % 8 == 0).
    const int P2 = blockIdx.x & 255;
    const int e  = blockIdx.x >> 8;
    const int b  = P2 >> 5;                       // 0..7
    const int dg = ((P2 & 31) << 1) | e;          // 0..63
    const int d  = dg * BD + dl;

    __shared__ float ldsP[NCHUNK * BD * 16];   // 32 KB (reused as H0)
    __shared__ float ldsS[NCHUNK * BD * 16];   // 32 KB

    bool pow_ok = true;
#pragma unroll
    for (int n = 0; n < 16; n++) {
        float An = -expf(A_log[d * 16 + n]);
        pow_ok = pow_ok && (fabsf(An + (float)(n + 1)) <= 1e-3f * (float)(n + 1));
    }
    float Wrow[16];
#pragma unroll
    for (int i = 0; i < 16; i += 4)
        *(float4*)&Wrow[i] = *(const float4*)(Wdt + d * 16 + i);
    const float bdtv = bdt[d];

    const int t0 = b * SEQ_LEN + ch * CHUNK;
    const int base = (ch * BD + dl) * 16;

    // ---- Phase A: local chunk scan (h0 = 0) ----
    float S[16];
#pragma unroll
    for (int n = 0; n < 16; n++) S[n] = 0.f;
    float sdt = 0.f;
#pragma unroll 2
    for (int t = 0; t < CHUNK; ++t) {
        const size_t row = (size_t)(t0 + t);
        const float* xr = xdbl + row * 48;
        float q[16], Bv[16];
#pragma unroll
        for (int i = 0; i < 16; i += 4) *(float4*)&q[i]  = *(const float4*)(xr + i);
#pragma unroll
        for (int i = 0; i < 16; i += 4) *(float4*)&Bv[i] = *(const float4*)(xr + 16 + i);
        float xcv = xc[row * 512 + d];
        float dot = bdtv;
#pragma unroll
        for (int i = 0; i < 16; i++) dot = fmaf(q[i], Wrow[i], dot);
        float dtv = softplusf(dot);
        sdt += dtv;
        float u = dtv * xcv;
        float p[16];
        if (pow_ok) {
            float e1 = expf(-dtv);
            p[0] = e1;
#pragma unroll
            for (int n = 1; n < 8; n++) p[n] = p[n - 1] * e1;
            float e8 = p[7];
#pragma unroll
            for (int n = 8; n < 16; n++) p[n] = p[n - 8] * e8;
        } else {
#pragma unroll
            for (int n = 0; n < 16; n++)
                p[n] = exp2f(dtv * (-expf(A_log[d * 16 + n])) * 1.44269504f);
        }
#pragma unroll
        for (int n = 0; n < 16; n++) S[n] = fmaf(p[n], S[n], u * Bv[n]);
    }
    {
        float p[16];
        if (pow_ok) {
            float e1 = expf(-sdt);
            p[0] = e1;
#pragma unroll
            for (int n = 1; n < 8; n++) p[n] = p[n - 1] * e1;
            float e8 = p[7];
#pragma unroll
            for (int n = 8; n < 16; n++) p[n] = p[n - 8] * e8;
        } else {
#pragma unroll
            for (int n = 0; n < 16; n++)
                p[n] = exp2f(sdt * (-expf(A_log[d * 16 + n])) * 1.44269504f);
        }
#pragma unroll
        for (int i = 0; i < 16; i += 4) {
            *(float4*)&ldsP[base + i] = *(float4*)&p[i];
            *(float4*)&ldsS[base + i] = *(float4*)&S[i];
        }
    }
    __syncthreads();

    // ---- Phase B: inter-chunk combine, one thread per (d,n) state ----
    if (tid < BD * 16) {
        const int dd = tid >> 4;
        const int nn = tid & 15;
        float h = 0.f;
#pragma unroll 4
        for (int c = 0; c < NCHUNK; ++c) {
            const int idx = (c * BD + dd) * 16 + nn;
            float Pv = ldsP[idx];
            float Sv = ldsS[idx];
            ldsP[idx] = h;                 // H0 overwrites P (already consumed)
            h = fmaf(Pv, h, Sv);
        }
    }
    __syncthreads();

    // ---- Phase C: re-scan with correct incoming state, emit y ----
    float h[16];
#pragma unroll
    for (int i = 0; i < 16; i += 4) *(float4*)&h[i] = *(float4*)&ldsP[base + i];
    const float Dd = Dp[d];
#pragma unroll 2
    for (int t = 0; t < CHUNK; ++t) {
        const size_t row = (size_t)(t0 + t);
        const float* xr = xdbl + row * 48;
        float q[16], Bv[16], Cv[16];
#pragma unroll
        for (int i = 0; i < 16; i += 4) *(float4*)&q[i]  = *(const float4*)(xr + i);
#pragma unroll
        for (int i = 0; i < 16; i += 4) *(float4*)&Bv[i] = *(const float4*)(xr + 16 + i);
#pragma unroll
        for (int i = 0; i < 16; i += 4) *(float4*)&Cv[i] = *(const float4*)(xr + 32 + i);
        float xcv = xc[row * 512 + d];
        float zv  = xz[row * 1024 + 512 + d];
        float dot = bdtv;
#pragma unroll
        for (int i = 0; i < 16; i++) dot = fmaf(q[i], Wrow[i], dot);
        float dtv = softplusf(dot);
        float u = dtv * xcv;
        float p[16];
        if (pow_ok) {
            float e1 = expf(-dtv);
            p[0] = e1;
#pragma unroll
            for (int n = 1; n < 8; n++) p[n] = p[n - 1] * e1;
            float e8 = p[7];
#pragma unroll
            for (int n = 8; n < 16; n++) p[n] = p[n - 8] * e8;
        } else {
#pragma unroll
            for (int n = 0; n < 16; n++)
                p[n] = exp2f(dtv * (-expf(A_log[d * 16 + n])) * 1.44269504f);
        }
        float y = 0.f;
#pragma unroll
        for (int n = 0; n < 16; n++) {
            h[n] = fmaf(p[n], h[n], u * Bv[n]);
            y = fmaf(h[n], Cv[n], y);
        }
        y = fmaf(Dd, xcv, y);
        y *= siluf(zv);
        xz[row * 1024 + d] = y;
    }
}

// LayerNorm over 256 features; one wave per row, 4 rows per block.
__global__ __launch_bounds__(256) void ln_k(
    const float* __restrict__ X, const float* __restrict__ g,
    const float* __restrict__ b2, float* __restrict__ Y)
{
    int lane = threadIdx.x & 63;
    int row = blockIdx.x * 4 + (threadIdx.x >> 6);
    const float4 v = *(const float4*)(X + (size_t)row * 256 + lane * 4);
    float s = v.x + v.y + v.z + v.w;
    float q = v.x * v.x + v.y * v.y + v.z * v.z + v.w * v.w;
#pragma unroll
    for (int o = 1; o < 64; o <<= 1) { s += __shfl_xor(s, o, 64); q += __shfl_xor(q, o, 64); }
    float mean = s * (1.f / 256.f);
    float var = q * (1.f / 256.f) - mean * mean;
    float inv = rsqrtf(var + 1e-5f);
    float4 gg = *(const float4*)(g + lane * 4);
    float4 bb = *(const float4*)(b2 + lane * 4);
    float4 o4;
    o4.x = (v.x - mean) * inv * gg.x + bb.x;
    o4.y = (v.y - mean) * inv * gg.y + bb.y;
    o4.z = (v.z - mean) * inv * gg.z + bb.z;
    o4.w = (v.w - mean) * inv * gg.w + bb.w;
    *(float4*)(Y + (size_t)row * 256 + lane * 4) = o4;
}

// mean over seq then dot with Wf + bf. one block per batch.
__global__ __launch_bounds__(256) void final_k(
    const float* __restrict__ H, const float* __restrict__ Wf,
    const float* __restrict__ bf, float* __restrict__ out)
{
    int b = blockIdx.x;
    int c = threadIdx.x;
    const float* p = H + (size_t)b * SEQ_LEN * 256 + c;
    float s = 0.f;
    for (int t = 0; t < SEQ_LEN; t++) s += p[t * 256];
    float v = s * (1.f / 1024.f) * Wf[c];
    int lane = c & 63;
#pragma unroll
    for (int o = 1; o < 64; o <<= 1) v += __shfl_xor(v, o, 64);
    __shared__ float red[4];
    if (lane == 0) red[c >> 6] = v;
    __syncthreads();
    if (c == 0) out[b] = red[0] + red[1] + red[2] + red[3] + bf[0];
}

extern "C" void kernel_launch(void* const* d_in, const int* in_sizes, int n_in,
                              void* d_out, int out_size, void* d_ws, size_t ws_size,
                              hipStream_t stream)
{
    const float* x      = (const float*)d_in[0];
    const float* Wp     = (const float*)d_in[1];
    const float* bp     = (const float*)d_in[2];
    const float* W_in   = (const float*)d_in[3];
    const float* conv_w = (const float*)d_in[4];
    const float* conv_b = (const float*)d_in[5];
    const float* W_x    = (const float*)d_in[6];
    const float* W_dt   = (const float*)d_in[7];
    const float* b_dt   = (const float*)d_in[8];
    const float* A_log  = (const float*)d_in[9];
    const float* Dp     = (const float*)d_in[10];
    const float* W_out  = (const float*)d_in[11];
    const float* ln_g   = (const float*)d_in[12];
    const float* ln_b   = (const float*)d_in[13];
    const float* Wf     = (const float*)d_in[14];
    const float* bf     = (const float*)d_in[15];

    float* ws = (float*)d_ws;
    float* bufXZ = ws;                             // 8192*1024
    float* bufXC = bufXZ + (size_t)ROWS * 1024;    // 8192*512
    float* bufXD = bufXC + (size_t)ROWS * 512;     // 8192*48
    float* bufH  = bufXD + (size_t)ROWS * 48;      // 8192*256
    float* bufO  = bufXC;                          // [ROWS][256] overlays dead xc

    dim3 blk(256);

    // h = x @ Wp^T + bp    (M=8192,N=256,K=64)
    gemm_mfma<<<dim3(2, 64), blk, 0, stream>>>(x, Wp, bp, bufH,
                                               ROWS, DMODEL, 64, 64, 64, DMODEL);

    for (int l = 0; l < 4; ++l) {
        const float* Wi  = W_in   + (size_t)l * 2 * DINNER * DMODEL;
        const float* cw  = conv_w + (size_t)l * DINNER * 4;
        const float* cb  = conv_b + (size_t)l * DINNER;
        const float* Wx  = W_x    + (size_t)l * (DTRANK + 2 * DSTATE) * DINNER;
        const float* Wdt = W_dt   + (size_t)l * DINNER * DTRANK;
        const float* bdt = b_dt   + (size_t)l * DINNER;
        const float* Al  = A_log  + (size_t)l * DINNER * DSTATE;
        const float* Dl  = Dp     + (size_t)l * DINNER;
        const float* Wo  = W_out  + (size_t)l * DMODEL * DINNER;
        const float* lg  = ln_g   + (size_t)l * DMODEL;
        const float* lb  = ln_b   + (size_t)l * DMODEL;

        // xz = h @ W_in^T   (N=1024, K=256)
        gemm_mfma<<<dim3(8, 64), blk, 0, stream>>>(bufH, Wi, nullptr, bufXZ,
                                                   ROWS, 1024, DMODEL, DMODEL, DMODEL, 1024);
        // conv + silu -> xc
        conv_silu_k<<<dim3(ROWS * DINNER / 256), blk, 0, stream>>>(bufXZ, cw, cb, bufXC);
        // x_dbl = xc @ W_x^T  (N=48, K=512)
        gemm_mfma<<<dim3(1, 64), blk, 0, stream>>>(bufXC, Wx, nullptr, bufXD,
                                                   ROWS, 48, DINNER, DINNER, DINNER, 48);
        // chunked selective scan (dt fused) -> y*silu(z) into bufXZ cols 0..511
        scan_k<<<dim3(512), dim3(512), 0, stream>>>(bufXC, bufXD, bufXZ,
                                                    Wdt, bdt, Al, Dl);
        // out = y @ W_out^T  (N=256, K=512, lda=1024) -> bufO (overlays xc)
        gemm_mfma<<<dim3(2, 64), blk, 0, stream>>>(bufXZ, Wo, nullptr, bufO,
                                                   ROWS, DMODEL, DINNER, 1024, DINNER, DMODEL);
        // layernorm -> bufH
        ln_k<<<dim3(ROWS / 4), blk, 0, stream>>>(bufO, lg, lb, bufH);
    }

    final_k<<<dim3(BATCH_N), blk, 0, stream>>>(bufH, Wf, bf, (float*)d_out);

    (void)in_sizes; (void)n_in; (void)out_size; (void)ws_size;
}

// Round 7
// 783.971 us; speedup vs baseline: 5.3712x; 1.0833x over previous
//
#include <hip/hip_runtime.h>
#include <hip/hip_bf16.h>
#include <math.h>

#define SEQ_LEN 1024
#define BATCH_N 8
#define DMODEL 256
#define DINNER 512
#define DSTATE 16
#define DTRANK 16
#define ROWS (BATCH_N * SEQ_LEN)   // 8192
#define NCHUNK 64
#define CHUNK (SEQ_LEN / NCHUNK)   // 16
#define BD 8                       // d-channels per block (scan)
#define LSTR 40                    // LDS row stride in ushorts (gemm staging)

typedef unsigned short u16;
typedef u16 u16x8 __attribute__((ext_vector_type(8)));
typedef short bf16x8 __attribute__((ext_vector_type(8)));
typedef float f32x4 __attribute__((ext_vector_type(4)));

__device__ __forceinline__ float siluf(float x) { return x / (1.f + expf(-x)); }
__device__ __forceinline__ float softplusf(float x) {
    return fmaxf(x, 0.f) + log1pf(expf(-fabsf(x)));
}

__device__ __forceinline__ u16 bf16_rne(float x) {
    unsigned u = __builtin_bit_cast(unsigned, x);
    return (u16)((u + 0x7FFFu + ((u >> 16) & 1u)) >> 16);
}
// split x -> hi (bf16 rne) + lo (bf16 rne of residual); hi+lo ~ x to 2^-17 rel
__device__ __forceinline__ void cvt_hl(float x, u16& h, u16& l) {
    unsigned u = __builtin_bit_cast(unsigned, x);
    unsigned hb = (u + 0x7FFFu + ((u >> 16) & 1u)) >> 16;
    h = (u16)hb;
    float hf = __builtin_bit_cast(float, hb << 16);
    l = bf16_rne(x - hf);
}
__device__ __forceinline__ float pair_f(u16 h, u16 l) {
    return __builtin_bit_cast(float, (unsigned)h << 16) +
           __builtin_bit_cast(float, (unsigned)l << 16);
}

// one-shot fp32 -> (hi,lo) bf16 pair conversion, 8 elems/thread
__global__ __launch_bounds__(256) void cvt_pairs_k(
    const float* __restrict__ src, u16* __restrict__ dh, u16* __restrict__ dl, int n8)
{
    int i = blockIdx.x * 256 + threadIdx.x;
    if (i >= n8) return;
    float4 a = ((const float4*)src)[i * 2];
    float4 b = ((const float4*)src)[i * 2 + 1];
    float v[8] = {a.x, a.y, a.z, a.w, b.x, b.y, b.z, b.w};
    u16 hs[8], ls[8];
#pragma unroll
    for (int j = 0; j < 8; j++) cvt_hl(v[j], hs[j], ls[j]);
    u16x8 h, l;
#pragma unroll
    for (int j = 0; j < 8; j++) { h[j] = hs[j]; l[j] = ls[j]; }
    *(u16x8*)(dh + i * 8) = h;
    *(u16x8*)(dl + i * 8) = l;
}

// ---------------------------------------------------------------------------
// Pair-bf16 MFMA GEMM: C[M,N] = A[M,K] @ B[N,K]^T (+bias), A/B given as
// pre-split bf16 hi/lo pair buffers. acc += Ah*Bh + Ah*Bl + Al*Bh (fp32 acc).
// 128x128 tile, 256 thr = 4 waves in 2x2; each wave 4x4 frags of 16x16x32.
// M % 128 == 0, K % 32 == 0 assumed; N guarded.
// EPI 0: fp32 C out.  EPI 1: hi/lo pair C out (Ch/Cl).
// ---------------------------------------------------------------------------
template<int EPI>
__global__ __launch_bounds__(256) void gemm_p(
    const u16* __restrict__ Ah, const u16* __restrict__ Al,
    const u16* __restrict__ Bh, const u16* __restrict__ Bl,
    const float* __restrict__ bias, float* __restrict__ C,
    u16* __restrict__ Ch, u16* __restrict__ Cl,
    int M, int N, int K, int lda, int ldb, int ldc)
{
    __shared__ u16 lds[4 * 128 * LSTR];   // Ahi Alo Bhi Blo = 40 KB
    u16* LAh = lds;
    u16* LAl = lds + 128 * LSTR;
    u16* LBh = lds + 2 * 128 * LSTR;
    u16* LBl = lds + 3 * 128 * LSTR;

    const int tid  = threadIdx.x;
    const int bm   = blockIdx.y * 128, bn = blockIdx.x * 128;
    const int wave = tid >> 6, lane = tid & 63;
    const int wm   = (wave >> 1) * 64, wn = (wave & 1) * 64;
    const int fr   = lane & 15;    // frag row (A-m / B-n)
    const int quad = lane >> 4;    // k-group

    f32x4 acc[4][4];
#pragma unroll
    for (int i = 0; i < 4; i++)
#pragma unroll
        for (int j = 0; j < 4; j++) acc[i][j] = (f32x4){0.f, 0.f, 0.f, 0.f};

    const int srow = tid >> 1;            // 0..127
    const int sk   = (tid & 1) * 16;      // 0 or 16
    const bool bvalid = (bn + srow) < N;
    const u16* pah = Ah + (size_t)(bm + srow) * lda + sk;
    const u16* pal = Al + (size_t)(bm + srow) * lda + sk;
    const u16* pbh = Bh + (size_t)(bn + srow) * ldb + sk;
    const u16* pbl = Bl + (size_t)(bn + srow) * ldb + sk;
    u16* wah = LAh + srow * LSTR + sk;
    u16* wal = LAl + srow * LSTR + sk;
    u16* wbh = LBh + srow * LSTR + sk;
    u16* wbl = LBl + srow * LSTR + sk;
    const u16x8 z8 = (u16x8){0,0,0,0,0,0,0,0};

    for (int k0 = 0; k0 < K; k0 += 32) {
#pragma unroll
        for (int j = 0; j < 16; j += 8) {
            *(u16x8*)(wah + j) = *(const u16x8*)(pah + k0 + j);
            *(u16x8*)(wal + j) = *(const u16x8*)(pal + k0 + j);
            *(u16x8*)(wbh + j) = bvalid ? *(const u16x8*)(pbh + k0 + j) : z8;
            *(u16x8*)(wbl + j) = bvalid ? *(const u16x8*)(pbl + k0 + j) : z8;
        }
        __syncthreads();

        bf16x8 ah[4], al[4], bh[4], bl[4];
#pragma unroll
        for (int i = 0; i < 4; i++) {
            const int ra = (wm + 16 * i + fr) * LSTR + quad * 8;
            const int rb = (wn + 16 * i + fr) * LSTR + quad * 8;
            ah[i] = *(const bf16x8*)(LAh + ra);
            al[i] = *(const bf16x8*)(LAl + ra);
            bh[i] = *(const bf16x8*)(LBh + rb);
            bl[i] = *(const bf16x8*)(LBl + rb);
        }
#pragma unroll
        for (int i = 0; i < 4; i++)
#pragma unroll
            for (int j = 0; j < 4; j++) {
                acc[i][j] = __builtin_amdgcn_mfma_f32_16x16x32_bf16(ah[i], bh[j], acc[i][j], 0, 0, 0);
                acc[i][j] = __builtin_amdgcn_mfma_f32_16x16x32_bf16(ah[i], bl[j], acc[i][j], 0, 0, 0);
                acc[i][j] = __builtin_amdgcn_mfma_f32_16x16x32_bf16(al[i], bh[j], acc[i][j], 0, 0, 0);
            }
        __syncthreads();
    }

    // C/D layout (m89-verified): row = quad*4 + reg, col = fr within 16x16 frag
#pragma unroll
    for (int i = 0; i < 4; i++) {
        const int r0 = bm + wm + 16 * i + quad * 4;
#pragma unroll
        for (int reg = 0; reg < 4; reg++) {
            const size_t rbase = (size_t)(r0 + reg) * ldc;
#pragma unroll
            for (int j = 0; j < 4; j++) {
                const int col = bn + wn + 16 * j + fr;
                if (col < N) {
                    float v = acc[i][j][reg];
                    if (bias) v += bias[col];
                    if (EPI == 0) {
                        C[rbase + col] = v;
                    } else {
                        u16 h, l;
                        cvt_hl(v, h, l);
                        Ch[rbase + col] = h;
                        Cl[rbase + col] = l;
                    }
                }
            }
        }
    }
}

// causal depthwise conv (k=4) + bias + silu -> bf16 hi/lo pair output.
// xz: [ROWS][1024], xh = cols 0..511
__global__ __launch_bounds__(256) void conv_silu_k(
    const float* __restrict__ xz, const float* __restrict__ cw,
    const float* __restrict__ cb, u16* __restrict__ xch, u16* __restrict__ xcl)
{
    int idx = blockIdx.x * 256 + threadIdx.x;
    int d = idx & (DINNER - 1);
    int row = idx >> 9;
    int t = row & (SEQ_LEN - 1);
    float4 w = *(const float4*)(cw + d * 4);
    float acc = cb[d];
    const float* p = xz + (size_t)row * 1024 + d;
    if (t >= 3) acc = fmaf(p[-3 * 1024], w.x, acc);
    if (t >= 2) acc = fmaf(p[-2 * 1024], w.y, acc);
    if (t >= 1) acc = fmaf(p[-1 * 1024], w.z, acc);
    acc = fmaf(p[0], w.w, acc);
    float v = siluf(acc);
    u16 h, l;
    cvt_hl(v, h, l);
    xch[idx] = h;
    xcl[idx] = l;
}

// ---------------------------------------------------------------------------
// Chunked selective scan with fused dt-projection.
// One thread per (b, d, chunk) carrying all 16 n-states in registers.
// Block: 512 threads = 8 d-lanes x 64 chunks. Grid 512 = 8 b x 64 dg,
// b = blk & 7 so each batch's blocks share one XCD (L2-resident re-reads).
// y output (bf16 hi/lo) overwrites xc in place — each (row,d) cell is owned
// by exactly one thread and read only in its own phases A/C before the write.
// ---------------------------------------------------------------------------
__global__ __launch_bounds__(512, 4) void scan_k(
    u16* __restrict__ xch,           // [ROWS][512] in: xc hi; out: y hi
    u16* __restrict__ xcl,           // [ROWS][512] in: xc lo; out: y lo
    const float* __restrict__ xdbl,  // [ROWS][48]  (dtr at 0, B at +16, C at +32)
    const float* __restrict__ xz,    // [ROWS][1024]  z at +512
    const float* __restrict__ Wdt,   // [512][16]
    const float* __restrict__ bdt,   // [512]
    const float* __restrict__ A_log, // [512][16]
    const float* __restrict__ Dp)    // [512]
{
    const int tid = threadIdx.x;
    const int dl  = tid & (BD - 1);      // 0..7
    const int ch  = tid >> 3;            // 0..63
    const int b   = blockIdx.x & 7;      // batch -> XCD partition
    const int dg  = blockIdx.x >> 3;     // 0..63
    const int d   = dg * BD + dl;

    __shared__ float ldsP[NCHUNK * BD * 16];   // 32 KB (reused as H0)
    __shared__ float ldsS[NCHUNK * BD * 16];   // 32 KB

    bool pow_ok = true;
#pragma unroll
    for (int n = 0; n < 16; n++) {
        float An = -expf(A_log[d * 16 + n]);
        pow_ok = pow_ok && (fabsf(An + (float)(n + 1)) <= 1e-3f * (float)(n + 1));
    }
    float Wrow[16];
#pragma unroll
    for (int i = 0; i < 16; i += 4)
        *(float4*)&Wrow[i] = *(const float4*)(Wdt + d * 16 + i);
    const float bdtv = bdt[d];

    const int t0 = b * SEQ_LEN + ch * CHUNK;
    const int base = (ch * BD + dl) * 16;

    // ---- Phase A: local chunk scan (h0 = 0) ----
    float S[16];
#pragma unroll
    for (int n = 0; n < 16; n++) S[n] = 0.f;
    float sdt = 0.f;
#pragma unroll 2
    for (int t = 0; t < CHUNK; ++t) {
        const size_t row = (size_t)(t0 + t);
        const float* xr = xdbl + row * 48;
        float q[16], Bv[16];
#pragma unroll
        for (int i = 0; i < 16; i += 4) *(float4*)&q[i]  = *(const float4*)(xr + i);
#pragma unroll
        for (int i = 0; i < 16; i += 4) *(float4*)&Bv[i] = *(const float4*)(xr + 16 + i);
        float xcv = pair_f(xch[row * 512 + d], xcl[row * 512 + d]);
        float dot = bdtv;
#pragma unroll
        for (int i = 0; i < 16; i++) dot = fmaf(q[i], Wrow[i], dot);
        float dtv = softplusf(dot);
        sdt += dtv;
        float u = dtv * xcv;
        float p[16];
        if (pow_ok) {
            float e1 = expf(-dtv);
            p[0] = e1;
#pragma unroll
            for (int n = 1; n < 8; n++) p[n] = p[n - 1] * e1;
            float e8 = p[7];
#pragma unroll
            for (int n = 8; n < 16; n++) p[n] = p[n - 8] * e8;
        } else {
#pragma unroll
            for (int n = 0; n < 16; n++)
                p[n] = exp2f(dtv * (-expf(A_log[d * 16 + n])) * 1.44269504f);
        }
#pragma unroll
        for (int n = 0; n < 16; n++) S[n] = fmaf(p[n], S[n], u * Bv[n]);
    }
    {
        float p[16];
        if (pow_ok) {
            float e1 = expf(-sdt);
            p[0] = e1;
#pragma unroll
            for (int n = 1; n < 8; n++) p[n] = p[n - 1] * e1;
            float e8 = p[7];
#pragma unroll
            for (int n = 8; n < 16; n++) p[n] = p[n - 8] * e8;
        } else {
#pragma unroll
            for (int n = 0; n < 16; n++)
                p[n] = exp2f(sdt * (-expf(A_log[d * 16 + n])) * 1.44269504f);
        }
#pragma unroll
        for (int i = 0; i < 16; i += 4) {
            *(float4*)&ldsP[base + i] = *(float4*)&p[i];
            *(float4*)&ldsS[base + i] = *(float4*)&S[i];
        }
    }
    __syncthreads();

    // ---- Phase B: inter-chunk combine, one thread per (d,n) state ----
    if (tid < BD * 16) {
        const int dd = tid >> 4;
        const int nn = tid & 15;
        float h = 0.f;
#pragma unroll 4
        for (int c = 0; c < NCHUNK; ++c) {
            const int idx = (c * BD + dd) * 16 + nn;
            float Pv = ldsP[idx];
            float Sv = ldsS[idx];
            ldsP[idx] = h;                 // H0 overwrites P (already consumed)
            h = fmaf(Pv, h, Sv);
        }
    }
    __syncthreads();

    // ---- Phase C: re-scan with correct incoming state, emit y (pair) ----
    float h[16];
#pragma unroll
    for (int i = 0; i < 16; i += 4) *(float4*)&h[i] = *(float4*)&ldsP[base + i];
    const float Dd = Dp[d];
#pragma unroll 2
    for (int t = 0; t < CHUNK; ++t) {
        const size_t row = (size_t)(t0 + t);
        const float* xr = xdbl + row * 48;
        float q[16], Bv[16], Cv[16];
#pragma unroll
        for (int i = 0; i < 16; i += 4) *(float4*)&q[i]  = *(const float4*)(xr + i);
#pragma unroll
        for (int i = 0; i < 16; i += 4) *(float4*)&Bv[i] = *(const float4*)(xr + 16 + i);
#pragma unroll
        for (int i = 0; i < 16; i += 4) *(float4*)&Cv[i] = *(const float4*)(xr + 32 + i);
        float xcv = pair_f(xch[row * 512 + d], xcl[row * 512 + d]);
        float zv  = xz[row * 1024 + 512 + d];
        float dot = bdtv;
#pragma unroll
        for (int i = 0; i < 16; i++) dot = fmaf(q[i], Wrow[i], dot);
        float dtv = softplusf(dot);
        float u = dtv * xcv;
        float p[16];
        if (pow_ok) {
            float e1 = expf(-dtv);
            p[0] = e1;
#pragma unroll
            for (int n = 1; n < 8; n++) p[n] = p[n - 1] * e1;
            float e8 = p[7];
#pragma unroll
            for (int n = 8; n < 16; n++) p[n] = p[n - 8] * e8;
        } else {
#pragma unroll
            for (int n = 0; n < 16; n++)
                p[n] = exp2f(dtv * (-expf(A_log[d * 16 + n])) * 1.44269504f);
        }
        float y = 0.f;
#pragma unroll
        for (int n = 0; n < 16; n++) {
            h[n] = fmaf(p[n], h[n], u * Bv[n]);
            y = fmaf(h[n], Cv[n], y);
        }
        y = fmaf(Dd, xcv, y);
        y *= siluf(zv);
        u16 yh, yl;
        cvt_hl(y, yh, yl);
        xch[row * 512 + d] = yh;
        xcl[row * 512 + d] = yl;
    }
}

// LayerNorm over 256 features -> bf16 hi/lo pair output; 4 rows per block.
__global__ __launch_bounds__(256) void ln_k(
    const float* __restrict__ X, const float* __restrict__ g,
    const float* __restrict__ b2, u16* __restrict__ Yh, u16* __restrict__ Yl)
{
    int lane = threadIdx.x & 63;
    int row = blockIdx.x * 4 + (threadIdx.x >> 6);
    const float4 v = *(const float4*)(X + (size_t)row * 256 + lane * 4);
    float s = v.x + v.y + v.z + v.w;
    float q = v.x * v.x + v.y * v.y + v.z * v.z + v.w * v.w;
#pragma unroll
    for (int o = 1; o < 64; o <<= 1) { s += __shfl_xor(s, o, 64); q += __shfl_xor(q, o, 64); }
    float mean = s * (1.f / 256.f);
    float var = q * (1.f / 256.f) - mean * mean;
    float inv = rsqrtf(var + 1e-5f);
    float4 gg = *(const float4*)(g + lane * 4);
    float4 bb = *(const float4*)(b2 + lane * 4);
    float o0 = (v.x - mean) * inv * gg.x + bb.x;
    float o1 = (v.y - mean) * inv * gg.y + bb.y;
    float o2 = (v.z - mean) * inv * gg.z + bb.z;
    float o3 = (v.w - mean) * inv * gg.w + bb.w;
    ushort4 h4, l4;
    cvt_hl(o0, h4.x, l4.x); cvt_hl(o1, h4.y, l4.y);
    cvt_hl(o2, h4.z, l4.z); cvt_hl(o3, h4.w, l4.w);
    *(ushort4*)(Yh + (size_t)row * 256 + lane * 4) = h4;
    *(ushort4*)(Yl + (size_t)row * 256 + lane * 4) = l4;
}

// mean over seq then dot with Wf + bf. one block per batch. pair input.
__global__ __launch_bounds__(256) void final_k(
    const u16* __restrict__ Hh, const u16* __restrict__ Hl,
    const float* __restrict__ Wf, const float* __restrict__ bf,
    float* __restrict__ out)
{
    int b = blockIdx.x;
    int c = threadIdx.x;
    const size_t base = (size_t)b * SEQ_LEN * 256 + c;
    float s = 0.f;
    for (int t = 0; t < SEQ_LEN; t++) s += pair_f(Hh[base + t * 256], Hl[base + t * 256]);
    float v = s * (1.f / 1024.f) * Wf[c];
    int lane = c & 63;
#pragma unroll
    for (int o = 1; o < 64; o <<= 1) v += __shfl_xor(v, o, 64);
    __shared__ float red[4];
    if (lane == 0) red[c >> 6] = v;
    __syncthreads();
    if (c == 0) out[b] = red[0] + red[1] + red[2] + red[3] + bf[0];
}

extern "C" void kernel_launch(void* const* d_in, const int* in_sizes, int n_in,
                              void* d_out, int out_size, void* d_ws, size_t ws_size,
                              hipStream_t stream)
{
    const float* x      = (const float*)d_in[0];
    const float* Wp     = (const float*)d_in[1];
    const float* bp     = (const float*)d_in[2];
    const float* W_in   = (const float*)d_in[3];
    const float* conv_w = (const float*)d_in[4];
    const float* conv_b = (const float*)d_in[5];
    const float* W_x    = (const float*)d_in[6];
    const float* W_dt   = (const float*)d_in[7];
    const float* b_dt   = (const float*)d_in[8];
    const float* A_log  = (const float*)d_in[9];
    const float* Dp     = (const float*)d_in[10];
    const float* W_out  = (const float*)d_in[11];
    const float* ln_g   = (const float*)d_in[12];
    const float* ln_b   = (const float*)d_in[13];
    const float* Wf     = (const float*)d_in[14];
    const float* bf     = (const float*)d_in[15];

    // ---- workspace layout (bytes) ----
    char* w = (char*)d_ws;
    float* bufXZ = (float*)w;            w += (size_t)ROWS * 1024 * 4;  // 33.55 MB
    float* bufXD = (float*)w;            w += (size_t)ROWS * 48 * 4;    // 1.57 MB
    u16* xch  = (u16*)w;                 w += (size_t)ROWS * 512 * 2;   // 8.39 MB
    u16* xcl  = (u16*)w;                 w += (size_t)ROWS * 512 * 2;
    u16* hh   = (u16*)w;                 w += (size_t)ROWS * 256 * 2;   // 4.19 MB
    u16* hl   = (u16*)w;                 w += (size_t)ROWS * 256 * 2;
    u16* xih  = (u16*)w;                 w += (size_t)ROWS * 64 * 2;    // 1.05 MB
    u16* xil  = (u16*)w;                 w += (size_t)ROWS * 64 * 2;
    u16* Wph  = (u16*)w;                 w += (size_t)DMODEL * 64 * 2;
    u16* Wpl  = (u16*)w;                 w += (size_t)DMODEL * 64 * 2;
    u16* Wih  = (u16*)w;                 w += (size_t)4 * 1024 * 256 * 2;  // 2.10 MB
    u16* Wil  = (u16*)w;                 w += (size_t)4 * 1024 * 256 * 2;
    u16* Wxh  = (u16*)w;                 w += (size_t)4 * 48 * 512 * 2;
    u16* Wxl  = (u16*)w;                 w += (size_t)4 * 48 * 512 * 2;
    u16* Woh  = (u16*)w;                 w += (size_t)4 * 256 * 512 * 2;
    u16* Wol  = (u16*)w;                 w += (size_t)4 * 256 * 512 * 2;
    float* bufO = bufXZ;   // [ROWS][256] overlays bufXZ (dead after scan)

    dim3 blk(256);

    // ---- one-shot conversions to bf16 pairs ----
    {
        int n;
        n = ROWS * 64 / 8;            cvt_pairs_k<<<dim3((n + 255) / 256), blk, 0, stream>>>(x, xih, xil, n);
        n = DMODEL * 64 / 8;          cvt_pairs_k<<<dim3((n + 255) / 256), blk, 0, stream>>>(Wp, Wph, Wpl, n);
        n = 4 * 1024 * 256 / 8;       cvt_pairs_k<<<dim3((n + 255) / 256), blk, 0, stream>>>(W_in, Wih, Wil, n);
        n = 4 * 48 * 512 / 8;         cvt_pairs_k<<<dim3((n + 255) / 256), blk, 0, stream>>>(W_x, Wxh, Wxl, n);
        n = 4 * 256 * 512 / 8;        cvt_pairs_k<<<dim3((n + 255) / 256), blk, 0, stream>>>(W_out, Woh, Wol, n);
    }

    // h = x @ Wp^T + bp  (M=8192,N=256,K=64) -> pair output
    gemm_p<1><<<dim3(2, 64), blk, 0, stream>>>(xih, xil, Wph, Wpl, bp,
                                               nullptr, hh, hl,
                                               ROWS, DMODEL, 64, 64, 64, DMODEL);

    for (int l = 0; l < 4; ++l) {
        const u16* Wihl = Wih + (size_t)l * 1024 * 256;
        const u16* Will = Wil + (size_t)l * 1024 * 256;
        const u16* Wxhl = Wxh + (size_t)l * 48 * 512;
        const u16* Wxll = Wxl + (size_t)l * 48 * 512;
        const u16* Wohl = Woh + (size_t)l * 256 * 512;
        const u16* Woll = Wol + (size_t)l * 256 * 512;
        const float* cw  = conv_w + (size_t)l * DINNER * 4;
        const float* cb  = conv_b + (size_t)l * DINNER;
        const float* Wdt = W_dt   + (size_t)l * DINNER * DTRANK;
        const float* bdt = b_dt   + (size_t)l * DINNER;
        const float* Al  = A_log  + (size_t)l * DINNER * DSTATE;
        const float* Dl  = Dp     + (size_t)l * DINNER;
        const float* lg  = ln_g   + (size_t)l * DMODEL;
        const float* lb  = ln_b   + (size_t)l * DMODEL;

        // xz = h @ W_in^T   (N=1024, K=256) -> fp32
        gemm_p<0><<<dim3(8, 64), blk, 0, stream>>>(hh, hl, Wihl, Will, nullptr,
                                                   bufXZ, nullptr, nullptr,
                                                   ROWS, 1024, DMODEL, DMODEL, DMODEL, 1024);
        // conv + silu -> xc pairs
        conv_silu_k<<<dim3(ROWS * DINNER / 256), blk, 0, stream>>>(bufXZ, cw, cb, xch, xcl);
        // x_dbl = xc @ W_x^T  (N=48, K=512) -> fp32
        gemm_p<0><<<dim3(1, 64), blk, 0, stream>>>(xch, xcl, Wxhl, Wxll, nullptr,
                                                   bufXD, nullptr, nullptr,
                                                   ROWS, 48, DINNER, DINNER, DINNER, 48);
        // chunked selective scan (dt fused) -> y pairs overwrite xc in place
        scan_k<<<dim3(512), dim3(512), 0, stream>>>(xch, xcl, bufXD, bufXZ,
                                                    Wdt, bdt, Al, Dl);
        // out = y @ W_out^T  (N=256, K=512) -> fp32 bufO (overlays dead bufXZ)
        gemm_p<0><<<dim3(2, 64), blk, 0, stream>>>(xch, xcl, Wohl, Woll, nullptr,
                                                   bufO, nullptr, nullptr,
                                                   ROWS, DMODEL, DINNER, DINNER, DINNER, DMODEL);
        // layernorm -> h pairs
        ln_k<<<dim3(ROWS / 4), blk, 0, stream>>>(bufO, lg, lb, hh, hl);
    }

    final_k<<<dim3(BATCH_N), blk, 0, stream>>>(hh, hl, Wf, bf, (float*)d_out);

    (void)in_sizes; (void)n_in; (void)out_size; (void)ws_size;
}